// Round 15
// baseline (114.227 us; speedup 1.0000x reference)
//
#include <hip/hip_runtime.h>

// Problem constants
#define NPOS 8192   // B*H*W = 8*32*32
#define CIN  512
#define EDIM 256
#define KCB  8192
#define HW   1024   // H*W

// MFMA-path constants
#define ESCALE 131072.0f         // 2^17: embed pre-scale so fp16 hi/lo normal
#define CINV   1.52587890625e-5f // 2/ESCALE = 2^-16 (exact pow2)
#define TAU2   1e-4f             // rescore margin >> quant grid + MFMA err
#define NSPLIT 16                // k-splits (512 k per block)
#define XSCALE 4.0f              // proj z pre-scale (keeps z_lo fp16-normal)
#define WSCALE 128.0f            // proj W pre-scale (keeps w_lo fp16-normal)
#define PDESC  (1.0f / 512.0f)   // 2^-9 = 1/(XSCALE*WSCALE), exact
#define KBIAS  8192.0f           // acc init bias: acc stays positive (55-sigma)

typedef _Float16 half8 __attribute__((ext_vector_type(8)));
typedef float    f32x4 __attribute__((ext_vector_type(4)));

// ---------------------------------------------------------------------------
// async global->LDS 16B: per-lane global src, wave-uniform LDS dest
// ---------------------------------------------------------------------------
__device__ __forceinline__ void gload16(const void* g, void* l)
{
    __builtin_amdgcn_global_load_lds(
        (__attribute__((address_space(1))) void*)g,
        (__attribute__((address_space(3))) void*)l, 16, 0, 0);
}

// min-domain top-2 merge (d values; smaller wins, tie -> lower idx)
__device__ __forceinline__ void top2_merge(float& v1, int& i1, float& v2, int& i2,
                                           float a1, int a1i, float a2, int a2i)
{
    bool aB = (a1 < v1) || (a1 == v1 && a1i < i1);
    if (aB) {
        bool s = (a2 < v1) || (a2 == v1 && a2i < i1);
        v2 = s ? a2 : v1; i2 = s ? a2i : i1;
        v1 = a1; i1 = a1i;
    } else {
        bool s = (v2 < a1) || (v2 == a1 && i2 < a1i);
        if (!s) { v2 = a1; i2 = a1i; }
    }
}

// ---------------------------------------------------------------------------
// Kernel PS: fragment-major hi/lo fp16 split of z (strided), W (row-major),
// and embed (hi only, ESCALE). grid 3136: z [0,2048) | w [2048,2112) |
// embed [2112,3136). (validated round 14; unchanged)
// ---------------------------------------------------------------------------
__global__ __launch_bounds__(256) void vq_proj_split_kernel(
    const float* __restrict__ z, const float* __restrict__ w,
    const float* __restrict__ embed,
    _Float16* __restrict__ zph, _Float16* __restrict__ zpl,
    _Float16* __restrict__ wph, _Float16* __restrict__ wpl,
    _Float16* __restrict__ geh)
{
    const int bx = blockIdx.x, tid = threadIdx.x;
    if (bx < 2048) {
        int gid = bx * 256 + tid;
        int fb = gid >> 6, lane = gid & 63;
        int n  = ((fb >> 4) << 4) + (lane & 15);
        int c0 = ((fb & 15) << 5) + (((lane >> 4) & 3) << 3);
        int b = n >> 10, hw = n & 1023;
        const float* p = z + (size_t)b * (CIN * HW) + hw;
        half8 h, l;
        #pragma unroll
        for (int j = 0; j < 8; ++j) {
            float x = p[(size_t)(c0 + j) * HW] * XSCALE;
            _Float16 hh = (_Float16)x;
            h[j] = hh;
            l[j] = (_Float16)(x - (float)hh);
        }
        *(half8*)(zph + (size_t)gid * 8) = h;
        *(half8*)(zpl + (size_t)gid * 8) = l;
    } else if (bx < 2112) {
        int gid = (bx - 2048) * 256 + tid;
        int fb = gid >> 6, lane = gid & 63;
        int e  = ((fb >> 4) << 4) + (lane & 15);
        int c0 = ((fb & 15) << 5) + (((lane >> 4) & 3) << 3);
        const float* p = w + (size_t)e * CIN + c0;
        half8 h, l;
        #pragma unroll
        for (int j = 0; j < 8; ++j) {
            float x = p[j] * WSCALE;
            _Float16 hh = (_Float16)x;
            h[j] = hh;
            l[j] = (_Float16)(x - (float)hh);
        }
        *(half8*)(wph + (size_t)gid * 8) = h;
        *(half8*)(wpl + (size_t)gid * 8) = l;
    } else {
        int gid = (bx - 2112) * 256 + tid;
        int fb = gid >> 6, lane = gid & 63;
        int n  = ((fb >> 3) << 4) + (lane & 15);
        int e0 = ((fb & 7) << 5) + (((lane >> 4) & 3) << 3);
        const float* p = embed + (size_t)n * EDIM + e0;
        float4 u = *(const float4*)p;
        float4 v = *(const float4*)(p + 4);
        float xs[8] = {u.x, u.y, u.z, u.w, v.x, v.y, v.z, v.w};
        half8 h;
        #pragma unroll
        for (int j = 0; j < 8; ++j)
            h[j] = (_Float16)(xs[j] * ESCALE);
        *(half8*)(geh + (size_t)gid * 8) = h;
    }
}

// ---------------------------------------------------------------------------
// Kernel PM: proj via 3-pass split-f16 MFMA (validated round 9; unchanged).
// ---------------------------------------------------------------------------
__global__ __launch_bounds__(256, 1) void vq_proj_mfma_kernel(
    const _Float16* __restrict__ zph, const _Float16* __restrict__ zpl,
    const _Float16* __restrict__ wph, const _Float16* __restrict__ wpl,
    const float* __restrict__ bias, float* __restrict__ ze)
{
    __shared__ __attribute__((aligned(16))) _Float16 sWh[2][2048];
    __shared__ __attribute__((aligned(16))) _Float16 sWl[2][2048];
    const int tid = threadIdx.x;
    const int w   = tid >> 6, lane = tid & 63;
    const int wr  = w >> 1,  wc   = w & 1;
    const int lm  = lane & 15, lg = lane >> 4;
    const int n0  = blockIdx.x * 64;
    const int e0  = blockIdx.y * 64;

    auto stageW = [&](int buf, int cb) {
        size_t fo = ((size_t)((e0 >> 4) + w) * 16 + cb) * 512 + (size_t)lane * 8;
        gload16(wph + fo, &sWh[buf][w * 512]);
        gload16(wpl + fo, &sWl[buf][w * 512]);
    };

    f32x4 acc[2][2];
    #pragma unroll
    for (int a = 0; a < 2; ++a)
        #pragma unroll
        for (int b = 0; b < 2; ++b) acc[a][b] = (f32x4){0.f, 0.f, 0.f, 0.f};

    stageW(0, 0);
    __syncthreads();

    #pragma unroll 1
    for (int cb = 0; cb < 16; ++cb) {
        const int cur = cb & 1;
        half8 aH[2], aL[2];
        #pragma unroll
        for (int ni = 0; ni < 2; ++ni) {
            size_t fo = ((size_t)((n0 >> 4) + wr * 2 + ni) * 16 + cb) * 512
                      + (size_t)lane * 8;
            aH[ni] = *(const half8*)(zph + fo);
            aL[ni] = *(const half8*)(zpl + fo);
        }
        if (cb + 1 < 16) stageW(cur ^ 1, cb + 1);
        half8 bH[2], bL[2];
        #pragma unroll
        for (int ej = 0; ej < 2; ++ej) {
            bH[ej] = *(const half8*)&sWh[cur][(wc * 2 + ej) * 512 + lane * 8];
            bL[ej] = *(const half8*)&sWl[cur][(wc * 2 + ej) * 512 + lane * 8];
        }
        #pragma unroll
        for (int ni = 0; ni < 2; ++ni)
            #pragma unroll
            for (int ej = 0; ej < 2; ++ej) {
                acc[ni][ej] = __builtin_amdgcn_mfma_f32_16x16x32_f16(aH[ni], bH[ej], acc[ni][ej], 0, 0, 0);
                acc[ni][ej] = __builtin_amdgcn_mfma_f32_16x16x32_f16(aH[ni], bL[ej], acc[ni][ej], 0, 0, 0);
                acc[ni][ej] = __builtin_amdgcn_mfma_f32_16x16x32_f16(aL[ni], bH[ej], acc[ni][ej], 0, 0, 0);
            }
        __syncthreads();
    }

    float bf[2];
    #pragma unroll
    for (int ej = 0; ej < 2; ++ej)
        bf[ej] = bias[e0 + wc * 32 + ej * 16 + lm];
    #pragma unroll
    for (int ni = 0; ni < 2; ++ni)
        #pragma unroll
        for (int ej = 0; ej < 2; ++ej) {
            int e = e0 + wc * 32 + ej * 16 + lm;
            #pragma unroll
            for (int r = 0; r < 4; ++r) {
                int n = n0 + wr * 32 + ni * 16 + lg * 4 + r;
                ze[(size_t)n * EDIM + e] = acc[ni][ej][r] * PDESC + bf[ej];
            }
        }
}

// ---------------------------------------------------------------------------
// Kernel P (prep, split-only): zq -> gxh (hi fp16, fragment-major).
// rownorm moved into vq_rrg (only the rescore needs it now).
// ---------------------------------------------------------------------------
__global__ __launch_bounds__(256) void vq_prep_kernel(
    const float* __restrict__ zq, _Float16* __restrict__ gxh)
{
    int gid = blockIdx.x * 256 + threadIdx.x;
    int fb = gid >> 6, lane = gid & 63;
    int n  = ((fb >> 3) << 4) + (lane & 15);
    int e0 = ((fb & 7) << 5) + (((lane >> 4) & 3) << 3);
    const float* p = zq + (size_t)n * EDIM + e0;
    float4 u = *(const float4*)p;
    float4 v = *(const float4*)(p + 4);
    float xs[8] = {u.x, u.y, u.z, u.w, v.x, v.y, v.z, v.w};
    half8 h;
    #pragma unroll
    for (int j = 0; j < 8; ++j)
        h[j] = (_Float16)xs[j];
    *(half8*)(gxh + (size_t)gid * 8) = h;
}

// ---------------------------------------------------------------------------
// Kernel M6: MFMA distance-argmin — M4b structure (8 waves, paired E staging,
// bias-baked keys) + FULL A-HOIST: the A (x) operand is k-invariant, so each
// thread loads its 16 half8 A fragments ONCE per block (was: re-read from L2
// every es step, 4x per block). Inner loop is pure {stage-B, ds_read, MFMA}.
// ep-loop fully unrolled so A[ni][es] indices are compile-time (rule #20 —
// runtime-indexed ext_vector arrays spill to scratch; round-5 scar).
// pv no longer includes rowA: pv = -2^-16 * v (exact) — all downstream
// comparisons are within-row, hence shift-invariant; grid-ties still flagged
// (gap <= g << TAU2) and resolved by the exact rescore (which adds An).
// ---------------------------------------------------------------------------
__global__ __launch_bounds__(512, 1) void vq_argmin_mfma6_kernel(
    const _Float16* __restrict__ gxh, const _Float16* __restrict__ geh,
    float* __restrict__ pv1, int* __restrict__ pi1,
    float* __restrict__ pv2, int* __restrict__ pi2)
{
    __shared__ __attribute__((aligned(16))) _Float16 sEh[2][8192];
    __shared__ unsigned cpk[2][128][2];

    const int tid  = threadIdx.x;
    const int w    = tid >> 6, lane = tid & 63;
    const int wr   = w >> 1,  wc   = w & 1;
    const int lm   = lane & 15, lg = lane >> 4;
    const int nb0  = blockIdx.x * 8;
    const int n0   = blockIdx.x * 128;
    const int kfb0 = blockIdx.y * 32;
    const int kbase = blockIdx.y * 512;

    auto stageE = [&](int buf, int p) {
        const int kt = p >> 2, ep = p & 3;
        const _Float16* src = geh
            + ((size_t)(kfb0 + kt * 8 + w) * 8 + ep * 2) * 512 + (size_t)lane * 8;
        gload16(src, &sEh[buf][w * 1024]);
        gload16(src + 512, &sEh[buf][w * 1024 + 512]);
    };

    // FULL A-HOIST: 2 frag rows x 8 es, loaded once (64 VGPR)
    const _Float16* pxh = gxh + (size_t)(nb0 + wr * 2) * 4096 + (size_t)lane * 8;
    half8 A[2][8];
    #pragma unroll
    for (int ni = 0; ni < 2; ++ni)
        #pragma unroll
        for (int es = 0; es < 8; ++es)
            A[ni][es] = *(const half8*)(pxh + (size_t)ni * 4096 + (size_t)es * 512);

    unsigned rp1[8], rp2[8];
    #pragma unroll
    for (int i = 0; i < 8; ++i) { rp1[i] = 0u; rp2[i] = 0u; }

    stageE(0, 0);
    __syncthreads();

    #pragma unroll 1
    for (int kt = 0; kt < 4; ++kt) {
        f32x4 acc[2][4];
        #pragma unroll
        for (int a = 0; a < 2; ++a)
            #pragma unroll
            for (int b = 0; b < 4; ++b)
                acc[a][b] = (f32x4){KBIAS, KBIAS, KBIAS, KBIAS};

        #pragma unroll
        for (int ep = 0; ep < 4; ++ep) {
            const int cur = ep & 1;            // (kt*4+ep)&1 == ep&1
            const int p = kt * 4 + ep;
            if (p + 1 < 16) stageE(cur ^ 1, p + 1);
            #pragma unroll
            for (int s = 0; s < 2; ++s) {
                const int es = ep * 2 + s;     // compile-time
                // kj pairs to keep transient regs short
                #pragma unroll
                for (int kp = 0; kp < 2; ++kp) {
                    half8 bv[2];
                    #pragma unroll
                    for (int j = 0; j < 2; ++j)
                        bv[j] = *(const half8*)&sEh[cur]
                            [(wc * 4 + kp * 2 + j) * 1024 + s * 512 + lane * 8];
                    #pragma unroll
                    for (int ni = 0; ni < 2; ++ni)
                        #pragma unroll
                        for (int j = 0; j < 2; ++j)
                            acc[ni][kp * 2 + j] = __builtin_amdgcn_mfma_f32_16x16x32_f16(
                                A[ni][es], bv[j], acc[ni][kp * 2 + j], 0, 0, 0);
                }
            }
            __syncthreads();
        }

        // fold k-tile into packed running top-2 (bias-baked keys)
        unsigned idxf[4];
        #pragma unroll
        for (int kj = 0; kj < 4; ++kj)
            idxf[kj] = (unsigned)(511 - (kt * 128 + wc * 64 + kj * 16 + lm));
        #pragma unroll
        for (int ni = 0; ni < 2; ++ni)
            #pragma unroll
            for (int r = 0; r < 4; ++r) {
                const int idx = ni * 4 + r;
                #pragma unroll
                for (int kj = 0; kj < 4; ++kj) {
                    unsigned key = (__float_as_uint(acc[ni][kj][r]) & ~0x1FFu)
                                 | idxf[kj];
                    unsigned hi = key > rp1[idx] ? key : rp1[idx];
                    unsigned lo = key > rp1[idx] ? rp1[idx] : key;
                    rp1[idx] = hi;
                    rp2[idx] = lo > rp2[idx] ? lo : rp2[idx];
                }
            }
    }

    // butterfly top-2 merge across the 16 lm lanes (packed keys)
    #pragma unroll
    for (int ni = 0; ni < 2; ++ni)
        #pragma unroll
        for (int r = 0; r < 4; ++r) {
            const int idx = ni * 4 + r;
            unsigned p1 = rp1[idx], p2 = rp2[idx];
            #pragma unroll
            for (int m = 8; m >= 1; m >>= 1) {
                unsigned o1 = (unsigned)__shfl_xor((int)p1, m);
                unsigned o2 = (unsigned)__shfl_xor((int)p2, m);
                unsigned np1 = p1 > o1 ? p1 : o1;
                unsigned lo  = p1 > o1 ? o1 : p1;
                unsigned hi2 = p2 > o2 ? p2 : o2;
                p2 = lo > hi2 ? lo : hi2;
                p1 = np1;
            }
            if (lm == 0) {
                int nl = wr * 32 + ni * 16 + lg * 4 + r;
                cpk[wc][nl][0] = p1;
                cpk[wc][nl][1] = p2;
            }
        }
    __syncthreads();
    if (tid < 128) {
        unsigned p1 = cpk[0][tid][0], p2 = cpk[0][tid][1];
        unsigned o1 = cpk[1][tid][0], o2 = cpk[1][tid][1];
        unsigned np1 = p1 > o1 ? p1 : o1;
        unsigned lo  = p1 > o1 ? o1 : p1;
        unsigned hi2 = p2 > o2 ? p2 : o2;
        p2 = lo > hi2 ? lo : hi2;
        p1 = np1;
        size_t o = (size_t)blockIdx.y * NPOS + n0 + tid;
        float v1 = __uint_as_float(p1 & ~0x1FFu) - KBIAS;  // Sterbenz-exact
        float v2 = __uint_as_float(p2 & ~0x1FFu) - KBIAS;
        pv1[o] = -CINV * v1;   // exact pow2 mul; An added only in rescore
        pi1[o] = kbase + 511 - (int)(p1 & 0x1FFu);
        pv2[o] = -CINV * v2;
        pi2[o] = kbase + 511 - (int)(p2 & 0x1FFu);
    }
}

// ---------------------------------------------------------------------------
// Kernel RRG (fused rownorm + reduce + rescore + gather + diff): grid 512,
// block 256, 16 rows/block.
// Phase 0: rowA for the block's 16 rows (same reduction order/bits as the
//   validated rownorm kernel) -> LDS sA.
// Phase 1: per-row 16-lane butterfly merge of NSPLIT top-2 lists; flag
//   gap <= TAU2 to LDS (~2.7 flagged rows/block).
// Phase 2: wave per flagged row, exact ascending-e fp32 fma rescore with
//   d = fma(-2, m, An) (bit-identical to the validated round-3 path).
// Phase 3: gather z_q = embed[idx], diff partial.
// ---------------------------------------------------------------------------
__global__ __launch_bounds__(256) void vq_rrg_kernel(
    const float* __restrict__ pv1, const int* __restrict__ pi1,
    const float* __restrict__ pv2, const int* __restrict__ pi2,
    const float* __restrict__ embed, float* __restrict__ zq,
    int* __restrict__ fidx, float* __restrict__ out_ind,
    float* __restrict__ partials)
{
    __shared__ int flg[16];
    __shared__ int sidx[16];
    __shared__ float sA[16];
    __shared__ int flgcnt;
    __shared__ float red[4];
    const int tid = threadIdx.x;
    const int n0 = blockIdx.x * 16;
    const int w = tid >> 6, lane = tid & 63;
    if (tid == 0) flgcnt = 0;
    __syncthreads();

    // phase 0: rowA for 16 rows (wave = 4 rows; order matches old rownorm)
    #pragma unroll
    for (int rr = 0; rr < 4; ++rr) {
        int r = w * 4 + rr;
        int n = n0 + r;
        float4 v = *(const float4*)(zq + (size_t)n * EDIM + lane * 4);
        float s = (v.x * v.x + v.y * v.y) + (v.z * v.z + v.w * v.w);
        #pragma unroll
        for (int off = 32; off >= 1; off >>= 1) s += __shfl_down(s, off);
        if (lane == 0) sA[r] = s;
    }

    // phase 1: merge 16 splits for 16 rows
    {
        int r = tid >> 4, s = tid & 15;
        int n = n0 + r;
        size_t o = (size_t)s * NPOS + n;
        float v1 = pv1[o], v2 = pv2[o];
        int i1 = pi1[o], i2 = pi2[o];
        #pragma unroll
        for (int m = 8; m >= 1; m >>= 1) {
            float ov1 = __shfl_xor(v1, m), ov2 = __shfl_xor(v2, m);
            int oi1 = __shfl_xor(i1, m), oi2 = __shfl_xor(i2, m);
            top2_merge(v1, i1, v2, i2, ov1, oi1, ov2, oi2);
        }
        if (s == 0) {
            sidx[r] = i1;
            fidx[n] = i1;
            out_ind[n] = (float)i1;
            if (v2 - v1 <= TAU2) {
                int q = atomicAdd(&flgcnt, 1);
                flg[q] = r;
            }
        }
    }
    __syncthreads();

    // phase 2: exact rescore of flagged rows (wave per row)
    const int cnt = flgcnt;
    for (int f = w; f < cnt; f += 4) {
        int r = flg[f];
        int n = n0 + r;
        float v = 3.4e38f; int k = 0x7fffffff;
        if (lane < 2 * NSPLIT) {
            size_t o = (size_t)(lane >> 1) * NPOS + n;
            v = (lane & 1) ? pv2[o] : pv1[o];
            k = (lane & 1) ? pi2[o] : pi1[o];
        }
        float vmin = v;
        #pragma unroll
        for (int m = 32; m >= 1; m >>= 1) vmin = fminf(vmin, __shfl_xor(vmin, m));
        float thr = vmin + TAU2;
        float An = sA[r];
        const float* xr = zq + (size_t)n * EDIM;
        float bd = 3.4e38f; int bk = 0x7fffffff;
        if (lane < 2 * NSPLIT && v <= thr) {
            const float* er = embed + (size_t)k * EDIM;
            float m_ = 0.f;
            for (int e = 0; e < EDIM; ++e) m_ = fmaf(xr[e], er[e], m_);
            bd = fmaf(-2.0f, m_, An);
            bk = k;
        }
        #pragma unroll
        for (int m = 32; m >= 1; m >>= 1) {
            float ov = __shfl_xor(bd, m);
            int   oi = __shfl_xor(bk, m);
            if (ov < bd || (ov == bd && oi < bk)) { bd = ov; bk = oi; }
        }
        if (lane == 0) {
            sidx[r] = bk;
            fidx[n] = bk;
            out_ind[n] = (float)bk;
        }
    }
    __syncthreads();

    // phase 3: gather + diff for the block's 16 rows (wave = 4 rows)
    float s = 0.f;
    #pragma unroll
    for (int rr = 0; rr < 4; ++rr) {
        int r = w * 4 + rr;
        int n = n0 + r;
        int idx = sidx[r];
        float4 e4 = *(const float4*)(embed + (size_t)idx * EDIM + lane * 4);
        float4 z4 = *(const float4*)(zq + (size_t)n * EDIM + lane * 4);
        float dx = e4.x - z4.x, dy = e4.y - z4.y;
        float dz = e4.z - z4.z, dw = e4.w - z4.w;
        s += (dx * dx + dy * dy) + (dz * dz + dw * dw);
        *(float4*)(zq + (size_t)n * EDIM + lane * 4) = e4;
    }
    #pragma unroll
    for (int off = 32; off >= 1; off >>= 1) s += __shfl_down(s, off);
    if (lane == 0) red[w] = s;
    __syncthreads();
    if (tid == 0) partials[blockIdx.x] = (red[0] + red[1]) + (red[2] + red[3]);
}

// ---------------------------------------------------------------------------
// Kernel F512: diff = sum(partials[512]) / (N*E)
// ---------------------------------------------------------------------------
__global__ __launch_bounds__(256) void vq_finalize512_kernel(
    const float* __restrict__ partials, float* __restrict__ out_diff)
{
    int tid = threadIdx.x;
    float s = partials[tid] + partials[tid + 256];
    __shared__ float red[4];
    #pragma unroll
    for (int off = 32; off >= 1; off >>= 1) s += __shfl_down(s, off);
    if ((tid & 63) == 0) red[tid >> 6] = s;
    __syncthreads();
    if (tid == 0)
        out_diff[0] = (red[0] + red[1] + red[2] + red[3]) / (float)(NPOS * EDIM);
}

// ---------------------------------------------------------------------------
// FALLBACK (round-3 validated fp32 path) — used when ws_size is too small.
// ---------------------------------------------------------------------------
__global__ __launch_bounds__(256) void vq_proj_kernel(
    const float* __restrict__ z, const float* __restrict__ w,
    const float* __restrict__ bias, float* __restrict__ ze)
{
    __shared__ float zs[16][68];
    __shared__ float wsh[16][68];
    const int tid = threadIdx.x;
    const int tx = tid & 15, ty = tid >> 4;
    const int n0 = blockIdx.x * 64;
    const int e0 = blockIdx.y * 64;
    const int b  = n0 >> 10;
    const int hw0 = n0 & 1023;
    const float* zb = z + (size_t)b * (CIN * HW) + hw0;

    float acc[4][4] = {};
    for (int cc = 0; cc < CIN; cc += 16) {
        #pragma unroll
        for (int j = 0; j < 4; ++j) {
            int i = tid + j * 256;
            int c = i >> 6, n = i & 63;
            zs[c][n] = zb[(size_t)(cc + c) * HW + n];
        }
        #pragma unroll
        for (int j = 0; j < 4; ++j) {
            int i = tid + j * 256;
            int c = i & 15, e = i >> 4;
            wsh[c][e] = w[(size_t)(e0 + e) * CIN + cc + c];
        }
        __syncthreads();
        #pragma unroll
        for (int c = 0; c < 16; ++c) {
            float4 xf4 = *(const float4*)&zs[c][ty * 4];
            float4 wf4 = *(const float4*)&wsh[c][tx * 4];
            float xf[4] = {xf4.x, xf4.y, xf4.z, xf4.w};
            float wf[4] = {wf4.x, wf4.y, wf4.z, wf4.w};
            #pragma unroll
            for (int i2 = 0; i2 < 4; ++i2)
                #pragma unroll
                for (int j2 = 0; j2 < 4; ++j2)
                    acc[i2][j2] += xf[i2] * wf[j2];
        }
        __syncthreads();
    }
    float bf[4];
    #pragma unroll
    for (int j2 = 0; j2 < 4; ++j2) bf[j2] = bias[e0 + tx * 4 + j2];
    #pragma unroll
    for (int i2 = 0; i2 < 4; ++i2) {
        int n = n0 + ty * 4 + i2;
        float4 v;
        v.x = acc[i2][0] + bf[0];
        v.y = acc[i2][1] + bf[1];
        v.z = acc[i2][2] + bf[2];
        v.w = acc[i2][3] + bf[3];
        *(float4*)(ze + (size_t)n * EDIM + e0 + tx * 4) = v;
    }
}

__global__ __launch_bounds__(256) void vq_rownorm_kernel(
    const float* __restrict__ ze, float* __restrict__ rowA)
{
    int n = blockIdx.x * 4 + (threadIdx.x >> 6);
    int lane = threadIdx.x & 63;
    float4 v = *(const float4*)(ze + (size_t)n * EDIM + lane * 4);
    float s = (v.x * v.x + v.y * v.y) + (v.z * v.z + v.w * v.w);
    #pragma unroll
    for (int off = 32; off >= 1; off >>= 1) s += __shfl_down(s, off);
    if (lane == 0) rowA[n] = s;
}

__global__ __launch_bounds__(256) void vq_argmin_kernel(
    const float* __restrict__ ze, const float* __restrict__ embed,
    const float* __restrict__ rowA,
    float* __restrict__ pval, int* __restrict__ pidx)
{
    __shared__ float xs[16][65];
    __shared__ float es[16][65];
    __shared__ float rowAs[64];
    const int tid = threadIdx.x;
    const int tx = tid & 15, ty = tid >> 4;
    const int n0 = blockIdx.x * 64;
    const int S = gridDim.y;
    const int KR = KCB / S;
    const int kbase = blockIdx.y * KR;

    if (tid < 64) rowAs[tid] = rowA[n0 + tid];
    __syncthreads();
    float Ar[4];
    #pragma unroll
    for (int i = 0; i < 4; ++i) Ar[i] = rowAs[ty * 4 + i];

    float minv[4];
    int   mini[4];
    #pragma unroll
    for (int i = 0; i < 4; ++i) { minv[i] = 3.4e38f; mini[i] = 0; }

    for (int kt = 0; kt < KR; kt += 64) {
        float acc[4][4] = {};
        for (int cc = 0; cc < EDIM; cc += 16) {
            {
                int n = tid >> 2, cp = (tid & 3) * 4;
                float4 v = *(const float4*)(ze + (size_t)(n0 + n) * EDIM + cc + cp);
                xs[cp + 0][n] = v.x; xs[cp + 1][n] = v.y;
                xs[cp + 2][n] = v.z; xs[cp + 3][n] = v.w;
            }
            {
                int k = tid >> 2, cp = (tid & 3) * 4;
                float4 v = *(const float4*)(embed + (size_t)(kbase + kt + k) * EDIM + cc + cp);
                es[cp + 0][k] = v.x; es[cp + 1][k] = v.y;
                es[cp + 2][k] = v.z; es[cp + 3][k] = v.w;
            }
            __syncthreads();
            #pragma unroll
            for (int c = 0; c < 16; ++c) {
                float xf[4], ef[4];
                #pragma unroll
                for (int i2 = 0; i2 < 4; ++i2) xf[i2] = xs[c][ty * 4 + i2];
                #pragma unroll
                for (int j2 = 0; j2 < 4; ++j2) ef[j2] = es[c][tx * 4 + j2];
                #pragma unroll
                for (int i2 = 0; i2 < 4; ++i2)
                    #pragma unroll
                    for (int j2 = 0; j2 < 4; ++j2)
                        acc[i2][j2] += xf[i2] * ef[j2];
            }
            __syncthreads();
        }
        #pragma unroll
        for (int j = 0; j < 4; ++j) {
            int k = kbase + kt + tx * 4 + j;
            #pragma unroll
            for (int i = 0; i < 4; ++i) {
                float d = Ar[i] - 2.0f * acc[i][j];
                if (d < minv[i]) { minv[i] = d; mini[i] = k; }
            }
        }
    }
    #pragma unroll
    for (int i = 0; i < 4; ++i) {
        float v = minv[i]; int ix = mini[i];
        #pragma unroll
        for (int m = 8; m >= 1; m >>= 1) {
            float ov = __shfl_xor(v, m);
            int   oi = __shfl_xor(ix, m);
            if (ov < v || (ov == v && oi < ix)) { v = ov; ix = oi; }
        }
        if (tx == 0) {
            int n = n0 + ty * 4 + i;
            pval[(size_t)blockIdx.y * NPOS + n] = v;
            pidx[(size_t)blockIdx.y * NPOS + n] = ix;
        }
    }
}

__global__ __launch_bounds__(256) void vq_reduce_argmin_kernel(
    const float* __restrict__ pval, const int* __restrict__ pidx,
    int S, int* __restrict__ fidx, float* __restrict__ out_ind)
{
    int n = blockIdx.x * 256 + threadIdx.x;
    float v = pval[n]; int ix = pidx[n];
    for (int ks = 1; ks < S; ++ks) {
        float ov = pval[(size_t)ks * NPOS + n];
        int   oi = pidx[(size_t)ks * NPOS + n];
        if (ov < v || (ov == v && oi < ix)) { v = ov; ix = oi; }
    }
    fidx[n] = ix;
    out_ind[n] = (float)ix;
}

__global__ __launch_bounds__(256) void vq_gather_diff_kernel(
    const float* __restrict__ embed, const int* __restrict__ fidx,
    float* __restrict__ zq, float* __restrict__ partials)
{
    int tid = threadIdx.x;
    int n0 = blockIdx.x * 32;
    float s = 0.f;
    for (int r = 0; r < 32; ++r) {
        int n = n0 + r;
        int idx = fidx[n];
        float e = embed[(size_t)idx * EDIM + tid];
        float v = zq[(size_t)n * EDIM + tid];
        float d = e - v;
        s += d * d;
        zq[(size_t)n * EDIM + tid] = e;
    }
    __shared__ float red[4];
    #pragma unroll
    for (int off = 32; off >= 1; off >>= 1) s += __shfl_down(s, off);
    if ((tid & 63) == 0) red[tid >> 6] = s;
    __syncthreads();
    if (tid == 0) partials[blockIdx.x] = red[0] + red[1] + red[2] + red[3];
}

__global__ __launch_bounds__(256) void vq_finalize_kernel(
    const float* __restrict__ partials, float* __restrict__ out_diff)
{
    int tid = threadIdx.x;
    float s = partials[tid];
    __shared__ float red[4];
    #pragma unroll
    for (int off = 32; off >= 1; off >>= 1) s += __shfl_down(s, off);
    if ((tid & 63) == 0) red[tid >> 6] = s;
    __syncthreads();
    if (tid == 0)
        out_diff[0] = (red[0] + red[1] + red[2] + red[3]) / (float)(NPOS * EDIM);
}

// ---------------------------------------------------------------------------
extern "C" void kernel_launch(void* const* d_in, const int* in_sizes, int n_in,
                              void* d_out, int out_size, void* d_ws, size_t ws_size,
                              hipStream_t stream)
{
    const float* z     = (const float*)d_in[0];
    const float* w     = (const float*)d_in[1];
    const float* bias  = (const float*)d_in[2];
    const float* embed = (const float*)d_in[3];

    float* out      = (float*)d_out;
    float* zq       = out;                       // [8192][256]; z_e then z_q
    float* out_diff = out + (size_t)NPOS * EDIM;
    float* out_ind  = out_diff + 1;              // [8192] indices as float

    char* wsb = (char*)d_ws;
    const size_t SZ_ZP   = (size_t)NPOS * CIN * 2;   // 8 MB (zph / zpl each)
    const size_t SZ_WP   = (size_t)EDIM * CIN * 2;   // 256 KB (wph / wpl each)
    const size_t SZ_GEH  = (size_t)KCB * EDIM * 2;   // 4 MB
    const size_t SZ_GXH  = (size_t)NPOS * EDIM * 2;  // 4 MB
    // layout: [phase A: zph zpl wph wpl | geh (persistent)]; phase B aliases
    // the zph/zpl region (gxh pv1 pi1 pv2 pi2 fidx partials ~6.1 MB < 16 MB).
    const size_t OFF_GEH = 2 * SZ_ZP + 2 * SZ_WP;    // 16.5 MB
    const size_t NEED = OFF_GEH + SZ_GEH;            // 20.5 MB (ws >= 25.3 MB proven r4)

    if (ws_size >= NEED) {
        // ---- MFMA path ----
        _Float16* zph = (_Float16*)wsb;
        _Float16* zpl = zph + SZ_ZP / 2;
        _Float16* wph = zpl + SZ_ZP / 2;
        _Float16* wpl = wph + SZ_WP / 2;
        _Float16* geh = (_Float16*)(wsb + OFF_GEH);
        // phase B (aliases zph/zpl region; starts after proj completes)
        _Float16* gxh  = (_Float16*)wsb;
        float*    pv1  = (float*)(wsb + SZ_GXH);
        int*      pi1  = (int*)(pv1 + (size_t)NSPLIT * NPOS);
        float*    pv2  = (float*)(pi1 + (size_t)NSPLIT * NPOS);
        int*      pi2  = (int*)(pv2 + (size_t)NSPLIT * NPOS);
        int*      fidx = (int*)(pi2 + (size_t)NSPLIT * NPOS);
        float*    partials = (float*)(fidx + NPOS);   // 512 floats

        vq_proj_split_kernel<<<dim3(3136), dim3(256), 0, stream>>>(
            z, w, embed, zph, zpl, wph, wpl, geh);
        vq_proj_mfma_kernel<<<dim3(128, 4), dim3(256), 0, stream>>>(
            zph, zpl, wph, wpl, bias, zq);
        vq_prep_kernel<<<dim3(1024), dim3(256), 0, stream>>>(zq, gxh);
        vq_argmin_mfma6_kernel<<<dim3(64, NSPLIT), dim3(512), 0, stream>>>(
            gxh, geh, pv1, pi1, pv2, pi2);
        vq_rrg_kernel<<<dim3(512), dim3(256), 0, stream>>>(
            pv1, pi1, pv2, pi2, embed, zq, fidx, out_ind, partials);
        vq_finalize512_kernel<<<dim3(1), dim3(256), 0, stream>>>(partials, out_diff);
    } else {
        // ---- fallback: round-3 validated fp32 path ----
        int S = 8;
        while (S > 1 && ws_size < (size_t)(2 * KCB + 256 + 2 * (size_t)S * NPOS) * 4) S >>= 1;
        float* W        = (float*)d_ws;
        float* rowA     = W;
        float* pval     = rowA + KCB;
        int*   pidx     = (int*)(pval + (size_t)S * NPOS);
        int*   fidx     = (int*)(pval + 2 * (size_t)S * NPOS);
        float* partials = (float*)(fidx + NPOS);

        vq_proj_kernel<<<dim3(128, 4), dim3(256), 0, stream>>>(z, w, bias, zq);
        vq_rownorm_kernel<<<dim3(2048), dim3(256), 0, stream>>>(zq, rowA);
        vq_argmin_kernel<<<dim3(128, S), dim3(256), 0, stream>>>(zq, embed, rowA, pval, pidx);
        vq_reduce_argmin_kernel<<<dim3(32), dim3(256), 0, stream>>>(pval, pidx, S, fidx, out_ind);
        vq_gather_diff_kernel<<<dim3(256), dim3(256), 0, stream>>>(embed, fidx, zq, partials);
        vq_finalize_kernel<<<dim3(1), dim3(256), 0, stream>>>(partials, out_diff);
    }
}

// Round 16
// 101.454 us; speedup vs baseline: 1.1259x; 1.1259x over previous
//
#include <hip/hip_runtime.h>

// Problem constants
#define NPOS 8192   // B*H*W = 8*32*32
#define CIN  512
#define EDIM 256
#define KCB  8192
#define HW   1024   // H*W

// MFMA-path constants
#define ESCALE 131072.0f         // 2^17: embed pre-scale so fp16 hi/lo normal
#define CINV   1.52587890625e-5f // 2/ESCALE = 2^-16 (exact pow2)
#define TAU2   1e-4f             // rescore margin >> quant grid + MFMA err
#define NSPLIT 16                // k-splits (512 k per block)
#define XSCALE 4.0f              // proj z pre-scale (keeps z_lo fp16-normal)
#define WSCALE 128.0f            // proj W pre-scale (keeps w_lo fp16-normal)
#define PDESC  (1.0f / 512.0f)   // 2^-9 = 1/(XSCALE*WSCALE), exact
#define KBIAS  8192.0f           // acc init bias: acc stays positive (55-sigma)

typedef _Float16 half8 __attribute__((ext_vector_type(8)));
typedef float    f32x4 __attribute__((ext_vector_type(4)));

// ---------------------------------------------------------------------------
// async global->LDS 16B: per-lane global src, wave-uniform LDS dest
// ---------------------------------------------------------------------------
__device__ __forceinline__ void gload16(const void* g, void* l)
{
    __builtin_amdgcn_global_load_lds(
        (__attribute__((address_space(1))) void*)g,
        (__attribute__((address_space(3))) void*)l, 16, 0, 0);
}

// min-domain top-2 merge (d values; smaller wins, tie -> lower idx)
__device__ __forceinline__ void top2_merge(float& v1, int& i1, float& v2, int& i2,
                                           float a1, int a1i, float a2, int a2i)
{
    bool aB = (a1 < v1) || (a1 == v1 && a1i < i1);
    if (aB) {
        bool s = (a2 < v1) || (a2 == v1 && a2i < i1);
        v2 = s ? a2 : v1; i2 = s ? a2i : i1;
        v1 = a1; i1 = a1i;
    } else {
        bool s = (v2 < a1) || (v2 == a1 && i2 < a1i);
        if (!s) { v2 = a1; i2 = a1i; }
    }
}

// ---------------------------------------------------------------------------
// Kernel PS: fragment-major hi/lo fp16 split of z (strided), W (row-major),
// and embed (hi only, ESCALE). grid 3136. (validated round 14; unchanged)
// ---------------------------------------------------------------------------
__global__ __launch_bounds__(256) void vq_proj_split_kernel(
    const float* __restrict__ z, const float* __restrict__ w,
    const float* __restrict__ embed,
    _Float16* __restrict__ zph, _Float16* __restrict__ zpl,
    _Float16* __restrict__ wph, _Float16* __restrict__ wpl,
    _Float16* __restrict__ geh)
{
    const int bx = blockIdx.x, tid = threadIdx.x;
    if (bx < 2048) {
        int gid = bx * 256 + tid;
        int fb = gid >> 6, lane = gid & 63;
        int n  = ((fb >> 4) << 4) + (lane & 15);
        int c0 = ((fb & 15) << 5) + (((lane >> 4) & 3) << 3);
        int b = n >> 10, hw = n & 1023;
        const float* p = z + (size_t)b * (CIN * HW) + hw;
        half8 h, l;
        #pragma unroll
        for (int j = 0; j < 8; ++j) {
            float x = p[(size_t)(c0 + j) * HW] * XSCALE;
            _Float16 hh = (_Float16)x;
            h[j] = hh;
            l[j] = (_Float16)(x - (float)hh);
        }
        *(half8*)(zph + (size_t)gid * 8) = h;
        *(half8*)(zpl + (size_t)gid * 8) = l;
    } else if (bx < 2112) {
        int gid = (bx - 2048) * 256 + tid;
        int fb = gid >> 6, lane = gid & 63;
        int e  = ((fb >> 4) << 4) + (lane & 15);
        int c0 = ((fb & 15) << 5) + (((lane >> 4) & 3) << 3);
        const float* p = w + (size_t)e * CIN + c0;
        half8 h, l;
        #pragma unroll
        for (int j = 0; j < 8; ++j) {
            float x = p[j] * WSCALE;
            _Float16 hh = (_Float16)x;
            h[j] = hh;
            l[j] = (_Float16)(x - (float)hh);
        }
        *(half8*)(wph + (size_t)gid * 8) = h;
        *(half8*)(wpl + (size_t)gid * 8) = l;
    } else {
        int gid = (bx - 2112) * 256 + tid;
        int fb = gid >> 6, lane = gid & 63;
        int n  = ((fb >> 3) << 4) + (lane & 15);
        int e0 = ((fb & 7) << 5) + (((lane >> 4) & 3) << 3);
        const float* p = embed + (size_t)n * EDIM + e0;
        float4 u = *(const float4*)p;
        float4 v = *(const float4*)(p + 4);
        float xs[8] = {u.x, u.y, u.z, u.w, v.x, v.y, v.z, v.w};
        half8 h;
        #pragma unroll
        for (int j = 0; j < 8; ++j)
            h[j] = (_Float16)(xs[j] * ESCALE);
        *(half8*)(geh + (size_t)gid * 8) = h;
    }
}

// ---------------------------------------------------------------------------
// Kernel PM: proj via 3-pass split-f16 MFMA (validated round 9; unchanged).
// ---------------------------------------------------------------------------
__global__ __launch_bounds__(256, 1) void vq_proj_mfma_kernel(
    const _Float16* __restrict__ zph, const _Float16* __restrict__ zpl,
    const _Float16* __restrict__ wph, const _Float16* __restrict__ wpl,
    const float* __restrict__ bias, float* __restrict__ ze)
{
    __shared__ __attribute__((aligned(16))) _Float16 sWh[2][2048];
    __shared__ __attribute__((aligned(16))) _Float16 sWl[2][2048];
    const int tid = threadIdx.x;
    const int w   = tid >> 6, lane = tid & 63;
    const int wr  = w >> 1,  wc   = w & 1;
    const int lm  = lane & 15, lg = lane >> 4;
    const int n0  = blockIdx.x * 64;
    const int e0  = blockIdx.y * 64;

    auto stageW = [&](int buf, int cb) {
        size_t fo = ((size_t)((e0 >> 4) + w) * 16 + cb) * 512 + (size_t)lane * 8;
        gload16(wph + fo, &sWh[buf][w * 512]);
        gload16(wpl + fo, &sWl[buf][w * 512]);
    };

    f32x4 acc[2][2];
    #pragma unroll
    for (int a = 0; a < 2; ++a)
        #pragma unroll
        for (int b = 0; b < 2; ++b) acc[a][b] = (f32x4){0.f, 0.f, 0.f, 0.f};

    stageW(0, 0);
    __syncthreads();

    #pragma unroll 1
    for (int cb = 0; cb < 16; ++cb) {
        const int cur = cb & 1;
        half8 aH[2], aL[2];
        #pragma unroll
        for (int ni = 0; ni < 2; ++ni) {
            size_t fo = ((size_t)((n0 >> 4) + wr * 2 + ni) * 16 + cb) * 512
                      + (size_t)lane * 8;
            aH[ni] = *(const half8*)(zph + fo);
            aL[ni] = *(const half8*)(zpl + fo);
        }
        if (cb + 1 < 16) stageW(cur ^ 1, cb + 1);
        half8 bH[2], bL[2];
        #pragma unroll
        for (int ej = 0; ej < 2; ++ej) {
            bH[ej] = *(const half8*)&sWh[cur][(wc * 2 + ej) * 512 + lane * 8];
            bL[ej] = *(const half8*)&sWl[cur][(wc * 2 + ej) * 512 + lane * 8];
        }
        #pragma unroll
        for (int ni = 0; ni < 2; ++ni)
            #pragma unroll
            for (int ej = 0; ej < 2; ++ej) {
                acc[ni][ej] = __builtin_amdgcn_mfma_f32_16x16x32_f16(aH[ni], bH[ej], acc[ni][ej], 0, 0, 0);
                acc[ni][ej] = __builtin_amdgcn_mfma_f32_16x16x32_f16(aH[ni], bL[ej], acc[ni][ej], 0, 0, 0);
                acc[ni][ej] = __builtin_amdgcn_mfma_f32_16x16x32_f16(aL[ni], bH[ej], acc[ni][ej], 0, 0, 0);
            }
        __syncthreads();
    }

    float bf[2];
    #pragma unroll
    for (int ej = 0; ej < 2; ++ej)
        bf[ej] = bias[e0 + wc * 32 + ej * 16 + lm];
    #pragma unroll
    for (int ni = 0; ni < 2; ++ni)
        #pragma unroll
        for (int ej = 0; ej < 2; ++ej) {
            int e = e0 + wc * 32 + ej * 16 + lm;
            #pragma unroll
            for (int r = 0; r < 4; ++r) {
                int n = n0 + wr * 32 + ni * 16 + lg * 4 + r;
                ze[(size_t)n * EDIM + e] = acc[ni][ej][r] * PDESC + bf[ej];
            }
        }
}

// ---------------------------------------------------------------------------
// Kernel P (prep, split-only): zq -> gxh (hi fp16, fragment-major).
// (validated round 15; unchanged)
// ---------------------------------------------------------------------------
__global__ __launch_bounds__(256) void vq_prep_kernel(
    const float* __restrict__ zq, _Float16* __restrict__ gxh)
{
    int gid = blockIdx.x * 256 + threadIdx.x;
    int fb = gid >> 6, lane = gid & 63;
    int n  = ((fb >> 3) << 4) + (lane & 15);
    int e0 = ((fb & 7) << 5) + (((lane >> 4) & 3) << 3);
    const float* p = zq + (size_t)n * EDIM + e0;
    float4 u = *(const float4*)p;
    float4 v = *(const float4*)(p + 4);
    float xs[8] = {u.x, u.y, u.z, u.w, v.x, v.y, v.z, v.w};
    half8 h;
    #pragma unroll
    for (int j = 0; j < 8; ++j)
        h[j] = (_Float16)xs[j];
    *(half8*)(gxh + (size_t)gid * 8) = h;
}

// ---------------------------------------------------------------------------
// Kernel M7: MFMA distance-argmin — the validated M4b structure (8 waves,
// per-es A loads from L2, paired E staging, bias-baked keys, 56 VGPR /
// 36% occupancy) + round-15's An-free pv epilogue (pv = -2^-16 * v, exact).
// ROUND-15 SCAR: full A-hoist (A[2][8], +28 VGPR) crossed the 64-VGPR
// occupancy cliff (m69) -> 36% -> 21% occupancy, argmin 49.5 -> 66 us.
// The per-es L2 A-loads ARE the cheap version; do not hoist them.
// ---------------------------------------------------------------------------
__global__ __launch_bounds__(512, 1) void vq_argmin_mfma7_kernel(
    const _Float16* __restrict__ gxh, const _Float16* __restrict__ geh,
    float* __restrict__ pv1, int* __restrict__ pi1,
    float* __restrict__ pv2, int* __restrict__ pi2)
{
    __shared__ __attribute__((aligned(16))) _Float16 sEh[2][8192];
    __shared__ unsigned cpk[2][128][2];

    const int tid  = threadIdx.x;
    const int w    = tid >> 6, lane = tid & 63;
    const int wr   = w >> 1,  wc   = w & 1;
    const int lm   = lane & 15, lg = lane >> 4;
    const int nb0  = blockIdx.x * 8;
    const int n0   = blockIdx.x * 128;
    const int kfb0 = blockIdx.y * 32;
    const int kbase = blockIdx.y * 512;

    auto stageE = [&](int buf, int p) {
        const int kt = p >> 2, ep = p & 3;
        const _Float16* src = geh
            + ((size_t)(kfb0 + kt * 8 + w) * 8 + ep * 2) * 512 + (size_t)lane * 8;
        gload16(src, &sEh[buf][w * 1024]);
        gload16(src + 512, &sEh[buf][w * 1024 + 512]);
    };

    const _Float16* pxh = gxh + (size_t)(nb0 + wr * 2) * 4096 + (size_t)lane * 8;

    unsigned rp1[8], rp2[8];
    #pragma unroll
    for (int i = 0; i < 8; ++i) { rp1[i] = 0u; rp2[i] = 0u; }

    stageE(0, 0);
    __syncthreads();

    int p = 0;
    #pragma unroll 1
    for (int kt = 0; kt < 4; ++kt) {
        f32x4 acc[2][4];
        #pragma unroll
        for (int a = 0; a < 2; ++a)
            #pragma unroll
            for (int b = 0; b < 4; ++b)
                acc[a][b] = (f32x4){KBIAS, KBIAS, KBIAS, KBIAS};

        #pragma unroll 1
        for (int ep = 0; ep < 4; ++ep, ++p) {
            const int cur = p & 1;
            if (p + 1 < 16) stageE(cur ^ 1, p + 1);
            #pragma unroll
            for (int s = 0; s < 2; ++s) {
                const int es = ep * 2 + s;
                half8 aH[2], bv[4];
                #pragma unroll
                for (int ni = 0; ni < 2; ++ni)
                    aH[ni] = *(const half8*)(pxh + (size_t)ni * 4096 + (size_t)es * 512);
                #pragma unroll
                for (int kj = 0; kj < 4; ++kj)
                    bv[kj] = *(const half8*)&sEh[cur][(wc * 4 + kj) * 1024 + s * 512 + lane * 8];
                #pragma unroll
                for (int ni = 0; ni < 2; ++ni)
                    #pragma unroll
                    for (int kj = 0; kj < 4; ++kj)
                        acc[ni][kj] = __builtin_amdgcn_mfma_f32_16x16x32_f16(aH[ni], bv[kj], acc[ni][kj], 0, 0, 0);
            }
            __syncthreads();
        }

        // fold k-tile into packed running top-2 (bias-baked keys)
        unsigned idxf[4];
        #pragma unroll
        for (int kj = 0; kj < 4; ++kj)
            idxf[kj] = (unsigned)(511 - (kt * 128 + wc * 64 + kj * 16 + lm));
        #pragma unroll
        for (int ni = 0; ni < 2; ++ni)
            #pragma unroll
            for (int r = 0; r < 4; ++r) {
                const int idx = ni * 4 + r;
                #pragma unroll
                for (int kj = 0; kj < 4; ++kj) {
                    unsigned key = (__float_as_uint(acc[ni][kj][r]) & ~0x1FFu)
                                 | idxf[kj];
                    unsigned hi = key > rp1[idx] ? key : rp1[idx];
                    unsigned lo = key > rp1[idx] ? rp1[idx] : key;
                    rp1[idx] = hi;
                    rp2[idx] = lo > rp2[idx] ? lo : rp2[idx];
                }
            }
    }

    // butterfly top-2 merge across the 16 lm lanes (packed keys)
    #pragma unroll
    for (int ni = 0; ni < 2; ++ni)
        #pragma unroll
        for (int r = 0; r < 4; ++r) {
            const int idx = ni * 4 + r;
            unsigned p1 = rp1[idx], p2 = rp2[idx];
            #pragma unroll
            for (int m = 8; m >= 1; m >>= 1) {
                unsigned o1 = (unsigned)__shfl_xor((int)p1, m);
                unsigned o2 = (unsigned)__shfl_xor((int)p2, m);
                unsigned np1 = p1 > o1 ? p1 : o1;
                unsigned lo  = p1 > o1 ? o1 : p1;
                unsigned hi2 = p2 > o2 ? p2 : o2;
                p2 = lo > hi2 ? lo : hi2;
                p1 = np1;
            }
            if (lm == 0) {
                int nl = wr * 32 + ni * 16 + lg * 4 + r;
                cpk[wc][nl][0] = p1;
                cpk[wc][nl][1] = p2;
            }
        }
    __syncthreads();
    if (tid < 128) {
        unsigned p1 = cpk[0][tid][0], p2 = cpk[0][tid][1];
        unsigned o1 = cpk[1][tid][0], o2 = cpk[1][tid][1];
        unsigned np1 = p1 > o1 ? p1 : o1;
        unsigned lo  = p1 > o1 ? o1 : p1;
        unsigned hi2 = p2 > o2 ? p2 : o2;
        p2 = lo > hi2 ? lo : hi2;
        p1 = np1;
        size_t o = (size_t)blockIdx.y * NPOS + n0 + tid;
        float v1 = __uint_as_float(p1 & ~0x1FFu) - KBIAS;  // Sterbenz-exact
        float v2 = __uint_as_float(p2 & ~0x1FFu) - KBIAS;
        pv1[o] = -CINV * v1;   // exact pow2 mul; An added only in rescore
        pi1[o] = kbase + 511 - (int)(p1 & 0x1FFu);
        pv2[o] = -CINV * v2;
        pi2[o] = kbase + 511 - (int)(p2 & 0x1FFu);
    }
}

// ---------------------------------------------------------------------------
// Kernel RRG (fused rownorm + reduce + rescore + gather + diff): grid 512,
// block 256, 16 rows/block. (validated round 15; unchanged)
// ---------------------------------------------------------------------------
__global__ __launch_bounds__(256) void vq_rrg_kernel(
    const float* __restrict__ pv1, const int* __restrict__ pi1,
    const float* __restrict__ pv2, const int* __restrict__ pi2,
    const float* __restrict__ embed, float* __restrict__ zq,
    int* __restrict__ fidx, float* __restrict__ out_ind,
    float* __restrict__ partials)
{
    __shared__ int flg[16];
    __shared__ int sidx[16];
    __shared__ float sA[16];
    __shared__ int flgcnt;
    __shared__ float red[4];
    const int tid = threadIdx.x;
    const int n0 = blockIdx.x * 16;
    const int w = tid >> 6, lane = tid & 63;
    if (tid == 0) flgcnt = 0;
    __syncthreads();

    // phase 0: rowA for 16 rows (wave = 4 rows; order matches old rownorm)
    #pragma unroll
    for (int rr = 0; rr < 4; ++rr) {
        int r = w * 4 + rr;
        int n = n0 + r;
        float4 v = *(const float4*)(zq + (size_t)n * EDIM + lane * 4);
        float s = (v.x * v.x + v.y * v.y) + (v.z * v.z + v.w * v.w);
        #pragma unroll
        for (int off = 32; off >= 1; off >>= 1) s += __shfl_down(s, off);
        if (lane == 0) sA[r] = s;
    }

    // phase 1: merge 16 splits for 16 rows
    {
        int r = tid >> 4, s = tid & 15;
        int n = n0 + r;
        size_t o = (size_t)s * NPOS + n;
        float v1 = pv1[o], v2 = pv2[o];
        int i1 = pi1[o], i2 = pi2[o];
        #pragma unroll
        for (int m = 8; m >= 1; m >>= 1) {
            float ov1 = __shfl_xor(v1, m), ov2 = __shfl_xor(v2, m);
            int oi1 = __shfl_xor(i1, m), oi2 = __shfl_xor(i2, m);
            top2_merge(v1, i1, v2, i2, ov1, oi1, ov2, oi2);
        }
        if (s == 0) {
            sidx[r] = i1;
            fidx[n] = i1;
            out_ind[n] = (float)i1;
            if (v2 - v1 <= TAU2) {
                int q = atomicAdd(&flgcnt, 1);
                flg[q] = r;
            }
        }
    }
    __syncthreads();

    // phase 2: exact rescore of flagged rows (wave per row)
    const int cnt = flgcnt;
    for (int f = w; f < cnt; f += 4) {
        int r = flg[f];
        int n = n0 + r;
        float v = 3.4e38f; int k = 0x7fffffff;
        if (lane < 2 * NSPLIT) {
            size_t o = (size_t)(lane >> 1) * NPOS + n;
            v = (lane & 1) ? pv2[o] : pv1[o];
            k = (lane & 1) ? pi2[o] : pi1[o];
        }
        float vmin = v;
        #pragma unroll
        for (int m = 32; m >= 1; m >>= 1) vmin = fminf(vmin, __shfl_xor(vmin, m));
        float thr = vmin + TAU2;
        float An = sA[r];
        const float* xr = zq + (size_t)n * EDIM;
        float bd = 3.4e38f; int bk = 0x7fffffff;
        if (lane < 2 * NSPLIT && v <= thr) {
            const float* er = embed + (size_t)k * EDIM;
            float m_ = 0.f;
            for (int e = 0; e < EDIM; ++e) m_ = fmaf(xr[e], er[e], m_);
            bd = fmaf(-2.0f, m_, An);
            bk = k;
        }
        #pragma unroll
        for (int m = 32; m >= 1; m >>= 1) {
            float ov = __shfl_xor(bd, m);
            int   oi = __shfl_xor(bk, m);
            if (ov < bd || (ov == bd && oi < bk)) { bd = ov; bk = oi; }
        }
        if (lane == 0) {
            sidx[r] = bk;
            fidx[n] = bk;
            out_ind[n] = (float)bk;
        }
    }
    __syncthreads();

    // phase 3: gather + diff for the block's 16 rows (wave = 4 rows)
    float s = 0.f;
    #pragma unroll
    for (int rr = 0; rr < 4; ++rr) {
        int r = w * 4 + rr;
        int n = n0 + r;
        int idx = sidx[r];
        float4 e4 = *(const float4*)(embed + (size_t)idx * EDIM + lane * 4);
        float4 z4 = *(const float4*)(zq + (size_t)n * EDIM + lane * 4);
        float dx = e4.x - z4.x, dy = e4.y - z4.y;
        float dz = e4.z - z4.z, dw = e4.w - z4.w;
        s += (dx * dx + dy * dy) + (dz * dz + dw * dw);
        *(float4*)(zq + (size_t)n * EDIM + lane * 4) = e4;
    }
    #pragma unroll
    for (int off = 32; off >= 1; off >>= 1) s += __shfl_down(s, off);
    if (lane == 0) red[w] = s;
    __syncthreads();
    if (tid == 0) partials[blockIdx.x] = (red[0] + red[1]) + (red[2] + red[3]);
}

// ---------------------------------------------------------------------------
// Kernel F512: diff = sum(partials[512]) / (N*E)
// ---------------------------------------------------------------------------
__global__ __launch_bounds__(256) void vq_finalize512_kernel(
    const float* __restrict__ partials, float* __restrict__ out_diff)
{
    int tid = threadIdx.x;
    float s = partials[tid] + partials[tid + 256];
    __shared__ float red[4];
    #pragma unroll
    for (int off = 32; off >= 1; off >>= 1) s += __shfl_down(s, off);
    if ((tid & 63) == 0) red[tid >> 6] = s;
    __syncthreads();
    if (tid == 0)
        out_diff[0] = (red[0] + red[1] + red[2] + red[3]) / (float)(NPOS * EDIM);
}

// ---------------------------------------------------------------------------
// FALLBACK (round-3 validated fp32 path) — used when ws_size is too small.
// ---------------------------------------------------------------------------
__global__ __launch_bounds__(256) void vq_proj_kernel(
    const float* __restrict__ z, const float* __restrict__ w,
    const float* __restrict__ bias, float* __restrict__ ze)
{
    __shared__ float zs[16][68];
    __shared__ float wsh[16][68];
    const int tid = threadIdx.x;
    const int tx = tid & 15, ty = tid >> 4;
    const int n0 = blockIdx.x * 64;
    const int e0 = blockIdx.y * 64;
    const int b  = n0 >> 10;
    const int hw0 = n0 & 1023;
    const float* zb = z + (size_t)b * (CIN * HW) + hw0;

    float acc[4][4] = {};
    for (int cc = 0; cc < CIN; cc += 16) {
        #pragma unroll
        for (int j = 0; j < 4; ++j) {
            int i = tid + j * 256;
            int c = i >> 6, n = i & 63;
            zs[c][n] = zb[(size_t)(cc + c) * HW + n];
        }
        #pragma unroll
        for (int j = 0; j < 4; ++j) {
            int i = tid + j * 256;
            int c = i & 15, e = i >> 4;
            wsh[c][e] = w[(size_t)(e0 + e) * CIN + cc + c];
        }
        __syncthreads();
        #pragma unroll
        for (int c = 0; c < 16; ++c) {
            float4 xf4 = *(const float4*)&zs[c][ty * 4];
            float4 wf4 = *(const float4*)&wsh[c][tx * 4];
            float xf[4] = {xf4.x, xf4.y, xf4.z, xf4.w};
            float wf[4] = {wf4.x, wf4.y, wf4.z, wf4.w};
            #pragma unroll
            for (int i2 = 0; i2 < 4; ++i2)
                #pragma unroll
                for (int j2 = 0; j2 < 4; ++j2)
                    acc[i2][j2] += xf[i2] * wf[j2];
        }
        __syncthreads();
    }
    float bf[4];
    #pragma unroll
    for (int j2 = 0; j2 < 4; ++j2) bf[j2] = bias[e0 + tx * 4 + j2];
    #pragma unroll
    for (int i2 = 0; i2 < 4; ++i2) {
        int n = n0 + ty * 4 + i2;
        float4 v;
        v.x = acc[i2][0] + bf[0];
        v.y = acc[i2][1] + bf[1];
        v.z = acc[i2][2] + bf[2];
        v.w = acc[i2][3] + bf[3];
        *(float4*)(ze + (size_t)n * EDIM + e0 + tx * 4) = v;
    }
}

__global__ __launch_bounds__(256) void vq_rownorm_kernel(
    const float* __restrict__ ze, float* __restrict__ rowA)
{
    int n = blockIdx.x * 4 + (threadIdx.x >> 6);
    int lane = threadIdx.x & 63;
    float4 v = *(const float4*)(ze + (size_t)n * EDIM + lane * 4);
    float s = (v.x * v.x + v.y * v.y) + (v.z * v.z + v.w * v.w);
    #pragma unroll
    for (int off = 32; off >= 1; off >>= 1) s += __shfl_down(s, off);
    if (lane == 0) rowA[n] = s;
}

__global__ __launch_bounds__(256) void vq_argmin_kernel(
    const float* __restrict__ ze, const float* __restrict__ embed,
    const float* __restrict__ rowA,
    float* __restrict__ pval, int* __restrict__ pidx)
{
    __shared__ float xs[16][65];
    __shared__ float es[16][65];
    __shared__ float rowAs[64];
    const int tid = threadIdx.x;
    const int tx = tid & 15, ty = tid >> 4;
    const int n0 = blockIdx.x * 64;
    const int S = gridDim.y;
    const int KR = KCB / S;
    const int kbase = blockIdx.y * KR;

    if (tid < 64) rowAs[tid] = rowA[n0 + tid];
    __syncthreads();
    float Ar[4];
    #pragma unroll
    for (int i = 0; i < 4; ++i) Ar[i] = rowAs[ty * 4 + i];

    float minv[4];
    int   mini[4];
    #pragma unroll
    for (int i = 0; i < 4; ++i) { minv[i] = 3.4e38f; mini[i] = 0; }

    for (int kt = 0; kt < KR; kt += 64) {
        float acc[4][4] = {};
        for (int cc = 0; cc < EDIM; cc += 16) {
            {
                int n = tid >> 2, cp = (tid & 3) * 4;
                float4 v = *(const float4*)(ze + (size_t)(n0 + n) * EDIM + cc + cp);
                xs[cp + 0][n] = v.x; xs[cp + 1][n] = v.y;
                xs[cp + 2][n] = v.z; xs[cp + 3][n] = v.w;
            }
            {
                int k = tid >> 2, cp = (tid & 3) * 4;
                float4 v = *(const float4*)(embed + (size_t)(kbase + kt + k) * EDIM + cc + cp);
                es[cp + 0][k] = v.x; es[cp + 1][k] = v.y;
                es[cp + 2][k] = v.z; es[cp + 3][k] = v.w;
            }
            __syncthreads();
            #pragma unroll
            for (int c = 0; c < 16; ++c) {
                float xf[4], ef[4];
                #pragma unroll
                for (int i2 = 0; i2 < 4; ++i2) xf[i2] = xs[c][ty * 4 + i2];
                #pragma unroll
                for (int j2 = 0; j2 < 4; ++j2) ef[j2] = es[c][tx * 4 + j2];
                #pragma unroll
                for (int i2 = 0; i2 < 4; ++i2)
                    #pragma unroll
                    for (int j2 = 0; j2 < 4; ++j2)
                        acc[i2][j2] += xf[i2] * ef[j2];
            }
            __syncthreads();
        }
        #pragma unroll
        for (int j = 0; j < 4; ++j) {
            int k = kbase + kt + tx * 4 + j;
            #pragma unroll
            for (int i = 0; i < 4; ++i) {
                float d = Ar[i] - 2.0f * acc[i][j];
                if (d < minv[i]) { minv[i] = d; mini[i] = k; }
            }
        }
    }
    #pragma unroll
    for (int i = 0; i < 4; ++i) {
        float v = minv[i]; int ix = mini[i];
        #pragma unroll
        for (int m = 8; m >= 1; m >>= 1) {
            float ov = __shfl_xor(v, m);
            int   oi = __shfl_xor(ix, m);
            if (ov < v || (ov == v && oi < ix)) { v = ov; ix = oi; }
        }
        if (tx == 0) {
            int n = n0 + ty * 4 + i;
            pval[(size_t)blockIdx.y * NPOS + n] = v;
            pidx[(size_t)blockIdx.y * NPOS + n] = ix;
        }
    }
}

__global__ __launch_bounds__(256) void vq_reduce_argmin_kernel(
    const float* __restrict__ pval, const int* __restrict__ pidx,
    int S, int* __restrict__ fidx, float* __restrict__ out_ind)
{
    int n = blockIdx.x * 256 + threadIdx.x;
    float v = pval[n]; int ix = pidx[n];
    for (int ks = 1; ks < S; ++ks) {
        float ov = pval[(size_t)ks * NPOS + n];
        int   oi = pidx[(size_t)ks * NPOS + n];
        if (ov < v || (ov == v && oi < ix)) { v = ov; ix = oi; }
    }
    fidx[n] = ix;
    out_ind[n] = (float)ix;
}

__global__ __launch_bounds__(256) void vq_gather_diff_kernel(
    const float* __restrict__ embed, const int* __restrict__ fidx,
    float* __restrict__ zq, float* __restrict__ partials)
{
    int tid = threadIdx.x;
    int n0 = blockIdx.x * 32;
    float s = 0.f;
    for (int r = 0; r < 32; ++r) {
        int n = n0 + r;
        int idx = fidx[n];
        float e = embed[(size_t)idx * EDIM + tid];
        float v = zq[(size_t)n * EDIM + tid];
        float d = e - v;
        s += d * d;
        zq[(size_t)n * EDIM + tid] = e;
    }
    __shared__ float red[4];
    #pragma unroll
    for (int off = 32; off >= 1; off >>= 1) s += __shfl_down(s, off);
    if ((tid & 63) == 0) red[tid >> 6] = s;
    __syncthreads();
    if (tid == 0) partials[blockIdx.x] = red[0] + red[1] + red[2] + red[3];
}

__global__ __launch_bounds__(256) void vq_finalize_kernel(
    const float* __restrict__ partials, float* __restrict__ out_diff)
{
    int tid = threadIdx.x;
    float s = partials[tid];
    __shared__ float red[4];
    #pragma unroll
    for (int off = 32; off >= 1; off >>= 1) s += __shfl_down(s, off);
    if ((tid & 63) == 0) red[tid >> 6] = s;
    __syncthreads();
    if (tid == 0)
        out_diff[0] = (red[0] + red[1] + red[2] + red[3]) / (float)(NPOS * EDIM);
}

// ---------------------------------------------------------------------------
extern "C" void kernel_launch(void* const* d_in, const int* in_sizes, int n_in,
                              void* d_out, int out_size, void* d_ws, size_t ws_size,
                              hipStream_t stream)
{
    const float* z     = (const float*)d_in[0];
    const float* w     = (const float*)d_in[1];
    const float* bias  = (const float*)d_in[2];
    const float* embed = (const float*)d_in[3];

    float* out      = (float*)d_out;
    float* zq       = out;                       // [8192][256]; z_e then z_q
    float* out_diff = out + (size_t)NPOS * EDIM;
    float* out_ind  = out_diff + 1;              // [8192] indices as float

    char* wsb = (char*)d_ws;
    const size_t SZ_ZP   = (size_t)NPOS * CIN * 2;   // 8 MB (zph / zpl each)
    const size_t SZ_WP   = (size_t)EDIM * CIN * 2;   // 256 KB (wph / wpl each)
    const size_t SZ_GEH  = (size_t)KCB * EDIM * 2;   // 4 MB
    const size_t SZ_GXH  = (size_t)NPOS * EDIM * 2;  // 4 MB
    // layout: [phase A: zph zpl wph wpl | geh (persistent)]; phase B aliases
    // the zph/zpl region (gxh pv1 pi1 pv2 pi2 fidx partials ~6.1 MB < 16 MB).
    const size_t OFF_GEH = 2 * SZ_ZP + 2 * SZ_WP;    // 16.5 MB
    const size_t NEED = OFF_GEH + SZ_GEH;            // 20.5 MB (ws >= 25.3 MB proven r4)

    if (ws_size >= NEED) {
        // ---- MFMA path ----
        _Float16* zph = (_Float16*)wsb;
        _Float16* zpl = zph + SZ_ZP / 2;
        _Float16* wph = zpl + SZ_ZP / 2;
        _Float16* wpl = wph + SZ_WP / 2;
        _Float16* geh = (_Float16*)(wsb + OFF_GEH);
        // phase B (aliases zph/zpl region; starts after proj completes)
        _Float16* gxh  = (_Float16*)wsb;
        float*    pv1  = (float*)(wsb + SZ_GXH);
        int*      pi1  = (int*)(pv1 + (size_t)NSPLIT * NPOS);
        float*    pv2  = (float*)(pi1 + (size_t)NSPLIT * NPOS);
        int*      pi2  = (int*)(pv2 + (size_t)NSPLIT * NPOS);
        int*      fidx = (int*)(pi2 + (size_t)NSPLIT * NPOS);
        float*    partials = (float*)(fidx + NPOS);   // 512 floats

        vq_proj_split_kernel<<<dim3(3136), dim3(256), 0, stream>>>(
            z, w, embed, zph, zpl, wph, wpl, geh);
        vq_proj_mfma_kernel<<<dim3(128, 4), dim3(256), 0, stream>>>(
            zph, zpl, wph, wpl, bias, zq);
        vq_prep_kernel<<<dim3(1024), dim3(256), 0, stream>>>(zq, gxh);
        vq_argmin_mfma7_kernel<<<dim3(64, NSPLIT), dim3(512), 0, stream>>>(
            gxh, geh, pv1, pi1, pv2, pi2);
        vq_rrg_kernel<<<dim3(512), dim3(256), 0, stream>>>(
            pv1, pi1, pv2, pi2, embed, zq, fidx, out_ind, partials);
        vq_finalize512_kernel<<<dim3(1), dim3(256), 0, stream>>>(partials, out_diff);
    } else {
        // ---- fallback: round-3 validated fp32 path ----
        int S = 8;
        while (S > 1 && ws_size < (size_t)(2 * KCB + 256 + 2 * (size_t)S * NPOS) * 4) S >>= 1;
        float* W        = (float*)d_ws;
        float* rowA     = W;
        float* pval     = rowA + KCB;
        int*   pidx     = (int*)(pval + (size_t)S * NPOS);
        int*   fidx     = (int*)(pval + 2 * (size_t)S * NPOS);
        float* partials = (float*)(fidx + NPOS);

        vq_proj_kernel<<<dim3(128, 4), dim3(256), 0, stream>>>(z, w, bias, zq);
        vq_rownorm_kernel<<<dim3(2048), dim3(256), 0, stream>>>(zq, rowA);
        vq_argmin_kernel<<<dim3(128, S), dim3(256), 0, stream>>>(zq, embed, rowA, pval, pidx);
        vq_reduce_argmin_kernel<<<dim3(32), dim3(256), 0, stream>>>(pval, pidx, S, fidx, out_ind);
        vq_gather_diff_kernel<<<dim3(256), dim3(256), 0, stream>>>(embed, fidx, zq, partials);
        vq_finalize_kernel<<<dim3(1), dim3(256), 0, stream>>>(partials, out_diff);
    }
}

// Round 17
// 98.274 us; speedup vs baseline: 1.1623x; 1.0324x over previous
//
#include <hip/hip_runtime.h>

// Problem constants
#define NPOS 8192   // B*H*W = 8*32*32
#define CIN  512
#define EDIM 256
#define KCB  8192
#define HW   1024   // H*W

// MFMA-path constants
#define ESCALE 131072.0f         // 2^17: embed pre-scale so fp16 hi/lo normal
#define CINV   1.52587890625e-5f // 2/ESCALE = 2^-16 (exact pow2)
#define TAU2   1e-4f             // rescore margin >> quant grid + MFMA err
#define NSPLIT 16                // k-splits (512 k per block)
#define XSCALE 4.0f              // proj z pre-scale (keeps z_lo fp16-normal)
#define WSCALE 128.0f            // proj W pre-scale (keeps w_lo fp16-normal)
#define PDESC  (1.0f / 512.0f)   // 2^-9 = 1/(XSCALE*WSCALE), exact
#define KBIAS  8192.0f           // acc init bias: acc stays positive (55-sigma)

typedef _Float16 half8 __attribute__((ext_vector_type(8)));
typedef float    f32x4 __attribute__((ext_vector_type(4)));

// ---------------------------------------------------------------------------
// async global->LDS 16B: per-lane global src, wave-uniform LDS dest
// ---------------------------------------------------------------------------
__device__ __forceinline__ void gload16(const void* g, void* l)
{
    __builtin_amdgcn_global_load_lds(
        (__attribute__((address_space(1))) void*)g,
        (__attribute__((address_space(3))) void*)l, 16, 0, 0);
}

// min-domain top-2 merge (d values; smaller wins, tie -> lower idx)
__device__ __forceinline__ void top2_merge(float& v1, int& i1, float& v2, int& i2,
                                           float a1, int a1i, float a2, int a2i)
{
    bool aB = (a1 < v1) || (a1 == v1 && a1i < i1);
    if (aB) {
        bool s = (a2 < v1) || (a2 == v1 && a2i < i1);
        v2 = s ? a2 : v1; i2 = s ? a2i : i1;
        v1 = a1; i1 = a1i;
    } else {
        bool s = (v2 < a1) || (v2 == a1 && i2 < a1i);
        if (!s) { v2 = a1; i2 = a1i; }
    }
}

// ---------------------------------------------------------------------------
// Kernel PS: fragment-major hi/lo fp16 split of z (strided), W (row-major),
// and embed (hi only, ESCALE). grid 3136. (validated round 14; unchanged)
// ---------------------------------------------------------------------------
__global__ __launch_bounds__(256) void vq_proj_split_kernel(
    const float* __restrict__ z, const float* __restrict__ w,
    const float* __restrict__ embed,
    _Float16* __restrict__ zph, _Float16* __restrict__ zpl,
    _Float16* __restrict__ wph, _Float16* __restrict__ wpl,
    _Float16* __restrict__ geh)
{
    const int bx = blockIdx.x, tid = threadIdx.x;
    if (bx < 2048) {
        int gid = bx * 256 + tid;
        int fb = gid >> 6, lane = gid & 63;
        int n  = ((fb >> 4) << 4) + (lane & 15);
        int c0 = ((fb & 15) << 5) + (((lane >> 4) & 3) << 3);
        int b = n >> 10, hw = n & 1023;
        const float* p = z + (size_t)b * (CIN * HW) + hw;
        half8 h, l;
        #pragma unroll
        for (int j = 0; j < 8; ++j) {
            float x = p[(size_t)(c0 + j) * HW] * XSCALE;
            _Float16 hh = (_Float16)x;
            h[j] = hh;
            l[j] = (_Float16)(x - (float)hh);
        }
        *(half8*)(zph + (size_t)gid * 8) = h;
        *(half8*)(zpl + (size_t)gid * 8) = l;
    } else if (bx < 2112) {
        int gid = (bx - 2048) * 256 + tid;
        int fb = gid >> 6, lane = gid & 63;
        int e  = ((fb >> 4) << 4) + (lane & 15);
        int c0 = ((fb & 15) << 5) + (((lane >> 4) & 3) << 3);
        const float* p = w + (size_t)e * CIN + c0;
        half8 h, l;
        #pragma unroll
        for (int j = 0; j < 8; ++j) {
            float x = p[j] * WSCALE;
            _Float16 hh = (_Float16)x;
            h[j] = hh;
            l[j] = (_Float16)(x - (float)hh);
        }
        *(half8*)(wph + (size_t)gid * 8) = h;
        *(half8*)(wpl + (size_t)gid * 8) = l;
    } else {
        int gid = (bx - 2112) * 256 + tid;
        int fb = gid >> 6, lane = gid & 63;
        int n  = ((fb >> 3) << 4) + (lane & 15);
        int e0 = ((fb & 7) << 5) + (((lane >> 4) & 3) << 3);
        const float* p = embed + (size_t)n * EDIM + e0;
        float4 u = *(const float4*)p;
        float4 v = *(const float4*)(p + 4);
        float xs[8] = {u.x, u.y, u.z, u.w, v.x, v.y, v.z, v.w};
        half8 h;
        #pragma unroll
        for (int j = 0; j < 8; ++j)
            h[j] = (_Float16)(xs[j] * ESCALE);
        *(half8*)(geh + (size_t)gid * 8) = h;
    }
}

// ---------------------------------------------------------------------------
// Kernel PM2: proj via 3-pass split-f16 MFMA (validated round 9 numerics,
// bit-identical ze) + FUSED gxh epilogue: the block's 64x66-padded z_e tile
// is staged in LDS, then re-read transposed to emit fragment-major fp16 gxh
// granules (coalesced 16B stores). gxh bits identical to the old prep kernel
// (fp16 of the same fp32 values it would have re-read from HBM) — deletes
// the prep kernel and its 12 MB of global traffic.
// Pad 66: write pattern (8*lg+lm) and read pattern (n+e) are both <=2-way
// bank aliasing = free (m136).
// ---------------------------------------------------------------------------
__global__ __launch_bounds__(256, 1) void vq_proj_mfma_kernel(
    const _Float16* __restrict__ zph, const _Float16* __restrict__ zpl,
    const _Float16* __restrict__ wph, const _Float16* __restrict__ wpl,
    const float* __restrict__ bias, float* __restrict__ ze,
    _Float16* __restrict__ gxh)
{
    __shared__ __attribute__((aligned(16))) _Float16 sWh[2][2048];
    __shared__ __attribute__((aligned(16))) _Float16 sWl[2][2048];
    __shared__ float sT[64][66];
    const int tid = threadIdx.x;
    const int w   = tid >> 6, lane = tid & 63;
    const int wr  = w >> 1,  wc   = w & 1;
    const int lm  = lane & 15, lg = lane >> 4;
    const int n0  = blockIdx.x * 64;
    const int e0  = blockIdx.y * 64;

    auto stageW = [&](int buf, int cb) {
        size_t fo = ((size_t)((e0 >> 4) + w) * 16 + cb) * 512 + (size_t)lane * 8;
        gload16(wph + fo, &sWh[buf][w * 512]);
        gload16(wpl + fo, &sWl[buf][w * 512]);
    };

    f32x4 acc[2][2];
    #pragma unroll
    for (int a = 0; a < 2; ++a)
        #pragma unroll
        for (int b = 0; b < 2; ++b) acc[a][b] = (f32x4){0.f, 0.f, 0.f, 0.f};

    stageW(0, 0);
    __syncthreads();

    #pragma unroll 1
    for (int cb = 0; cb < 16; ++cb) {
        const int cur = cb & 1;
        half8 aH[2], aL[2];
        #pragma unroll
        for (int ni = 0; ni < 2; ++ni) {
            size_t fo = ((size_t)((n0 >> 4) + wr * 2 + ni) * 16 + cb) * 512
                      + (size_t)lane * 8;
            aH[ni] = *(const half8*)(zph + fo);
            aL[ni] = *(const half8*)(zpl + fo);
        }
        if (cb + 1 < 16) stageW(cur ^ 1, cb + 1);
        half8 bH[2], bL[2];
        #pragma unroll
        for (int ej = 0; ej < 2; ++ej) {
            bH[ej] = *(const half8*)&sWh[cur][(wc * 2 + ej) * 512 + lane * 8];
            bL[ej] = *(const half8*)&sWl[cur][(wc * 2 + ej) * 512 + lane * 8];
        }
        #pragma unroll
        for (int ni = 0; ni < 2; ++ni)
            #pragma unroll
            for (int ej = 0; ej < 2; ++ej) {
                acc[ni][ej] = __builtin_amdgcn_mfma_f32_16x16x32_f16(aH[ni], bH[ej], acc[ni][ej], 0, 0, 0);
                acc[ni][ej] = __builtin_amdgcn_mfma_f32_16x16x32_f16(aH[ni], bL[ej], acc[ni][ej], 0, 0, 0);
                acc[ni][ej] = __builtin_amdgcn_mfma_f32_16x16x32_f16(aL[ni], bH[ej], acc[ni][ej], 0, 0, 0);
            }
        __syncthreads();
    }

    // epilogue A: descale + bias; write fp32 ze AND stage tile in LDS
    float bf[2];
    #pragma unroll
    for (int ej = 0; ej < 2; ++ej)
        bf[ej] = bias[e0 + wc * 32 + ej * 16 + lm];
    #pragma unroll
    for (int ni = 0; ni < 2; ++ni)
        #pragma unroll
        for (int ej = 0; ej < 2; ++ej) {
            int el = wc * 32 + ej * 16 + lm;
            #pragma unroll
            for (int r = 0; r < 4; ++r) {
                int nl = wr * 32 + ni * 16 + lg * 4 + r;
                float v = acc[ni][ej][r] * PDESC + bf[ej];
                ze[(size_t)(n0 + nl) * EDIM + e0 + el] = v;
                sT[nl][el] = v;
            }
        }
    __syncthreads();

    // epilogue B: transposed read -> fragment-major fp16 gxh (coalesced)
    #pragma unroll
    for (int q = 0; q < 2; ++q) {
        int gran = tid + q * 256;
        int frag = gran >> 6, ln = gran & 63;
        int a = frag >> 1, b = frag & 1;
        int nl = a * 16 + (ln & 15);
        int el = b * 32 + ((ln >> 4) & 3) * 8;
        half8 h;
        #pragma unroll
        for (int j = 0; j < 8; ++j)
            h[j] = (_Float16)sT[nl][el + j];
        size_t fb = (size_t)((n0 >> 4) + a) * 8 + (e0 >> 5) + b;
        *(half8*)(gxh + fb * 512 + (size_t)ln * 8) = h;
    }
}

// ---------------------------------------------------------------------------
// Kernel M7: MFMA distance-argmin (validated round 16; unchanged).
// 8 waves, per-es A loads from L2, paired E staging, bias-baked keys,
// 56 VGPR / 37% occupancy, An-free pv epilogue.
// SCARS: (256,2) bound -> spill (r5); 4-wave rebalance -> latency (r13);
// A-hoist -> 64-VGPR occupancy cliff (r15). Do not touch the loop body.
// ---------------------------------------------------------------------------
__global__ __launch_bounds__(512, 1) void vq_argmin_mfma7_kernel(
    const _Float16* __restrict__ gxh, const _Float16* __restrict__ geh,
    float* __restrict__ pv1, int* __restrict__ pi1,
    float* __restrict__ pv2, int* __restrict__ pi2)
{
    __shared__ __attribute__((aligned(16))) _Float16 sEh[2][8192];
    __shared__ unsigned cpk[2][128][2];

    const int tid  = threadIdx.x;
    const int w    = tid >> 6, lane = tid & 63;
    const int wr   = w >> 1,  wc   = w & 1;
    const int lm   = lane & 15, lg = lane >> 4;
    const int nb0  = blockIdx.x * 8;
    const int n0   = blockIdx.x * 128;
    const int kfb0 = blockIdx.y * 32;
    const int kbase = blockIdx.y * 512;

    auto stageE = [&](int buf, int p) {
        const int kt = p >> 2, ep = p & 3;
        const _Float16* src = geh
            + ((size_t)(kfb0 + kt * 8 + w) * 8 + ep * 2) * 512 + (size_t)lane * 8;
        gload16(src, &sEh[buf][w * 1024]);
        gload16(src + 512, &sEh[buf][w * 1024 + 512]);
    };

    const _Float16* pxh = gxh + (size_t)(nb0 + wr * 2) * 4096 + (size_t)lane * 8;

    unsigned rp1[8], rp2[8];
    #pragma unroll
    for (int i = 0; i < 8; ++i) { rp1[i] = 0u; rp2[i] = 0u; }

    stageE(0, 0);
    __syncthreads();

    int p = 0;
    #pragma unroll 1
    for (int kt = 0; kt < 4; ++kt) {
        f32x4 acc[2][4];
        #pragma unroll
        for (int a = 0; a < 2; ++a)
            #pragma unroll
            for (int b = 0; b < 4; ++b)
                acc[a][b] = (f32x4){KBIAS, KBIAS, KBIAS, KBIAS};

        #pragma unroll 1
        for (int ep = 0; ep < 4; ++ep, ++p) {
            const int cur = p & 1;
            if (p + 1 < 16) stageE(cur ^ 1, p + 1);
            #pragma unroll
            for (int s = 0; s < 2; ++s) {
                const int es = ep * 2 + s;
                half8 aH[2], bv[4];
                #pragma unroll
                for (int ni = 0; ni < 2; ++ni)
                    aH[ni] = *(const half8*)(pxh + (size_t)ni * 4096 + (size_t)es * 512);
                #pragma unroll
                for (int kj = 0; kj < 4; ++kj)
                    bv[kj] = *(const half8*)&sEh[cur][(wc * 4 + kj) * 1024 + s * 512 + lane * 8];
                #pragma unroll
                for (int ni = 0; ni < 2; ++ni)
                    #pragma unroll
                    for (int kj = 0; kj < 4; ++kj)
                        acc[ni][kj] = __builtin_amdgcn_mfma_f32_16x16x32_f16(aH[ni], bv[kj], acc[ni][kj], 0, 0, 0);
            }
            __syncthreads();
        }

        // fold k-tile into packed running top-2 (bias-baked keys)
        unsigned idxf[4];
        #pragma unroll
        for (int kj = 0; kj < 4; ++kj)
            idxf[kj] = (unsigned)(511 - (kt * 128 + wc * 64 + kj * 16 + lm));
        #pragma unroll
        for (int ni = 0; ni < 2; ++ni)
            #pragma unroll
            for (int r = 0; r < 4; ++r) {
                const int idx = ni * 4 + r;
                #pragma unroll
                for (int kj = 0; kj < 4; ++kj) {
                    unsigned key = (__float_as_uint(acc[ni][kj][r]) & ~0x1FFu)
                                 | idxf[kj];
                    unsigned hi = key > rp1[idx] ? key : rp1[idx];
                    unsigned lo = key > rp1[idx] ? rp1[idx] : key;
                    rp1[idx] = hi;
                    rp2[idx] = lo > rp2[idx] ? lo : rp2[idx];
                }
            }
    }

    // butterfly top-2 merge across the 16 lm lanes (packed keys)
    #pragma unroll
    for (int ni = 0; ni < 2; ++ni)
        #pragma unroll
        for (int r = 0; r < 4; ++r) {
            const int idx = ni * 4 + r;
            unsigned p1 = rp1[idx], p2 = rp2[idx];
            #pragma unroll
            for (int m = 8; m >= 1; m >>= 1) {
                unsigned o1 = (unsigned)__shfl_xor((int)p1, m);
                unsigned o2 = (unsigned)__shfl_xor((int)p2, m);
                unsigned np1 = p1 > o1 ? p1 : o1;
                unsigned lo  = p1 > o1 ? o1 : p1;
                unsigned hi2 = p2 > o2 ? p2 : o2;
                p2 = lo > hi2 ? lo : hi2;
                p1 = np1;
            }
            if (lm == 0) {
                int nl = wr * 32 + ni * 16 + lg * 4 + r;
                cpk[wc][nl][0] = p1;
                cpk[wc][nl][1] = p2;
            }
        }
    __syncthreads();
    if (tid < 128) {
        unsigned p1 = cpk[0][tid][0], p2 = cpk[0][tid][1];
        unsigned o1 = cpk[1][tid][0], o2 = cpk[1][tid][1];
        unsigned np1 = p1 > o1 ? p1 : o1;
        unsigned lo  = p1 > o1 ? o1 : p1;
        unsigned hi2 = p2 > o2 ? p2 : o2;
        p2 = lo > hi2 ? lo : hi2;
        p1 = np1;
        size_t o = (size_t)blockIdx.y * NPOS + n0 + tid;
        float v1 = __uint_as_float(p1 & ~0x1FFu) - KBIAS;  // Sterbenz-exact
        float v2 = __uint_as_float(p2 & ~0x1FFu) - KBIAS;
        pv1[o] = -CINV * v1;   // exact pow2 mul; An added only in rescore
        pi1[o] = kbase + 511 - (int)(p1 & 0x1FFu);
        pv2[o] = -CINV * v2;
        pi2[o] = kbase + 511 - (int)(p2 & 0x1FFu);
    }
}

// ---------------------------------------------------------------------------
// Kernel RRG (fused rownorm + reduce + rescore + gather + diff): grid 512,
// block 256, 16 rows/block. (validated round 15/16; unchanged)
// ---------------------------------------------------------------------------
__global__ __launch_bounds__(256) void vq_rrg_kernel(
    const float* __restrict__ pv1, const int* __restrict__ pi1,
    const float* __restrict__ pv2, const int* __restrict__ pi2,
    const float* __restrict__ embed, float* __restrict__ zq,
    int* __restrict__ fidx, float* __restrict__ out_ind,
    float* __restrict__ partials)
{
    __shared__ int flg[16];
    __shared__ int sidx[16];
    __shared__ float sA[16];
    __shared__ int flgcnt;
    __shared__ float red[4];
    const int tid = threadIdx.x;
    const int n0 = blockIdx.x * 16;
    const int w = tid >> 6, lane = tid & 63;
    if (tid == 0) flgcnt = 0;
    __syncthreads();

    // phase 0: rowA for 16 rows (wave = 4 rows; order matches old rownorm)
    #pragma unroll
    for (int rr = 0; rr < 4; ++rr) {
        int r = w * 4 + rr;
        int n = n0 + r;
        float4 v = *(const float4*)(zq + (size_t)n * EDIM + lane * 4);
        float s = (v.x * v.x + v.y * v.y) + (v.z * v.z + v.w * v.w);
        #pragma unroll
        for (int off = 32; off >= 1; off >>= 1) s += __shfl_down(s, off);
        if (lane == 0) sA[r] = s;
    }

    // phase 1: merge 16 splits for 16 rows
    {
        int r = tid >> 4, s = tid & 15;
        int n = n0 + r;
        size_t o = (size_t)s * NPOS + n;
        float v1 = pv1[o], v2 = pv2[o];
        int i1 = pi1[o], i2 = pi2[o];
        #pragma unroll
        for (int m = 8; m >= 1; m >>= 1) {
            float ov1 = __shfl_xor(v1, m), ov2 = __shfl_xor(v2, m);
            int oi1 = __shfl_xor(i1, m), oi2 = __shfl_xor(i2, m);
            top2_merge(v1, i1, v2, i2, ov1, oi1, ov2, oi2);
        }
        if (s == 0) {
            sidx[r] = i1;
            fidx[n] = i1;
            out_ind[n] = (float)i1;
            if (v2 - v1 <= TAU2) {
                int q = atomicAdd(&flgcnt, 1);
                flg[q] = r;
            }
        }
    }
    __syncthreads();

    // phase 2: exact rescore of flagged rows (wave per row)
    const int cnt = flgcnt;
    for (int f = w; f < cnt; f += 4) {
        int r = flg[f];
        int n = n0 + r;
        float v = 3.4e38f; int k = 0x7fffffff;
        if (lane < 2 * NSPLIT) {
            size_t o = (size_t)(lane >> 1) * NPOS + n;
            v = (lane & 1) ? pv2[o] : pv1[o];
            k = (lane & 1) ? pi2[o] : pi1[o];
        }
        float vmin = v;
        #pragma unroll
        for (int m = 32; m >= 1; m >>= 1) vmin = fminf(vmin, __shfl_xor(vmin, m));
        float thr = vmin + TAU2;
        float An = sA[r];
        const float* xr = zq + (size_t)n * EDIM;
        float bd = 3.4e38f; int bk = 0x7fffffff;
        if (lane < 2 * NSPLIT && v <= thr) {
            const float* er = embed + (size_t)k * EDIM;
            float m_ = 0.f;
            for (int e = 0; e < EDIM; ++e) m_ = fmaf(xr[e], er[e], m_);
            bd = fmaf(-2.0f, m_, An);
            bk = k;
        }
        #pragma unroll
        for (int m = 32; m >= 1; m >>= 1) {
            float ov = __shfl_xor(bd, m);
            int   oi = __shfl_xor(bk, m);
            if (ov < bd || (ov == bd && oi < bk)) { bd = ov; bk = oi; }
        }
        if (lane == 0) {
            sidx[r] = bk;
            fidx[n] = bk;
            out_ind[n] = (float)bk;
        }
    }
    __syncthreads();

    // phase 3: gather + diff for the block's 16 rows (wave = 4 rows)
    float s = 0.f;
    #pragma unroll
    for (int rr = 0; rr < 4; ++rr) {
        int r = w * 4 + rr;
        int n = n0 + r;
        int idx = sidx[r];
        float4 e4 = *(const float4*)(embed + (size_t)idx * EDIM + lane * 4);
        float4 z4 = *(const float4*)(zq + (size_t)n * EDIM + lane * 4);
        float dx = e4.x - z4.x, dy = e4.y - z4.y;
        float dz = e4.z - z4.z, dw = e4.w - z4.w;
        s += (dx * dx + dy * dy) + (dz * dz + dw * dw);
        *(float4*)(zq + (size_t)n * EDIM + lane * 4) = e4;
    }
    #pragma unroll
    for (int off = 32; off >= 1; off >>= 1) s += __shfl_down(s, off);
    if (lane == 0) red[w] = s;
    __syncthreads();
    if (tid == 0) partials[blockIdx.x] = (red[0] + red[1]) + (red[2] + red[3]);
}

// ---------------------------------------------------------------------------
// Kernel F512: diff = sum(partials[512]) / (N*E)
// ---------------------------------------------------------------------------
__global__ __launch_bounds__(256) void vq_finalize512_kernel(
    const float* __restrict__ partials, float* __restrict__ out_diff)
{
    int tid = threadIdx.x;
    float s = partials[tid] + partials[tid + 256];
    __shared__ float red[4];
    #pragma unroll
    for (int off = 32; off >= 1; off >>= 1) s += __shfl_down(s, off);
    if ((tid & 63) == 0) red[tid >> 6] = s;
    __syncthreads();
    if (tid == 0)
        out_diff[0] = (red[0] + red[1] + red[2] + red[3]) / (float)(NPOS * EDIM);
}

// ---------------------------------------------------------------------------
// FALLBACK (round-3 validated fp32 path) — used when ws_size is too small.
// ---------------------------------------------------------------------------
__global__ __launch_bounds__(256) void vq_proj_kernel(
    const float* __restrict__ z, const float* __restrict__ w,
    const float* __restrict__ bias, float* __restrict__ ze)
{
    __shared__ float zs[16][68];
    __shared__ float wsh[16][68];
    const int tid = threadIdx.x;
    const int tx = tid & 15, ty = tid >> 4;
    const int n0 = blockIdx.x * 64;
    const int e0 = blockIdx.y * 64;
    const int b  = n0 >> 10;
    const int hw0 = n0 & 1023;
    const float* zb = z + (size_t)b * (CIN * HW) + hw0;

    float acc[4][4] = {};
    for (int cc = 0; cc < CIN; cc += 16) {
        #pragma unroll
        for (int j = 0; j < 4; ++j) {
            int i = tid + j * 256;
            int c = i >> 6, n = i & 63;
            zs[c][n] = zb[(size_t)(cc + c) * HW + n];
        }
        #pragma unroll
        for (int j = 0; j < 4; ++j) {
            int i = tid + j * 256;
            int c = i & 15, e = i >> 4;
            wsh[c][e] = w[(size_t)(e0 + e) * CIN + cc + c];
        }
        __syncthreads();
        #pragma unroll
        for (int c = 0; c < 16; ++c) {
            float4 xf4 = *(const float4*)&zs[c][ty * 4];
            float4 wf4 = *(const float4*)&wsh[c][tx * 4];
            float xf[4] = {xf4.x, xf4.y, xf4.z, xf4.w};
            float wf[4] = {wf4.x, wf4.y, wf4.z, wf4.w};
            #pragma unroll
            for (int i2 = 0; i2 < 4; ++i2)
                #pragma unroll
                for (int j2 = 0; j2 < 4; ++j2)
                    acc[i2][j2] += xf[i2] * wf[j2];
        }
        __syncthreads();
    }
    float bf[4];
    #pragma unroll
    for (int j2 = 0; j2 < 4; ++j2) bf[j2] = bias[e0 + tx * 4 + j2];
    #pragma unroll
    for (int i2 = 0; i2 < 4; ++i2) {
        int n = n0 + ty * 4 + i2;
        float4 v;
        v.x = acc[i2][0] + bf[0];
        v.y = acc[i2][1] + bf[1];
        v.z = acc[i2][2] + bf[2];
        v.w = acc[i2][3] + bf[3];
        *(float4*)(ze + (size_t)n * EDIM + e0 + tx * 4) = v;
    }
}

__global__ __launch_bounds__(256) void vq_rownorm_kernel(
    const float* __restrict__ ze, float* __restrict__ rowA)
{
    int n = blockIdx.x * 4 + (threadIdx.x >> 6);
    int lane = threadIdx.x & 63;
    float4 v = *(const float4*)(ze + (size_t)n * EDIM + lane * 4);
    float s = (v.x * v.x + v.y * v.y) + (v.z * v.z + v.w * v.w);
    #pragma unroll
    for (int off = 32; off >= 1; off >>= 1) s += __shfl_down(s, off);
    if (lane == 0) rowA[n] = s;
}

__global__ __launch_bounds__(256) void vq_argmin_kernel(
    const float* __restrict__ ze, const float* __restrict__ embed,
    const float* __restrict__ rowA,
    float* __restrict__ pval, int* __restrict__ pidx)
{
    __shared__ float xs[16][65];
    __shared__ float es[16][65];
    __shared__ float rowAs[64];
    const int tid = threadIdx.x;
    const int tx = tid & 15, ty = tid >> 4;
    const int n0 = blockIdx.x * 64;
    const int S = gridDim.y;
    const int KR = KCB / S;
    const int kbase = blockIdx.y * KR;

    if (tid < 64) rowAs[tid] = rowA[n0 + tid];
    __syncthreads();
    float Ar[4];
    #pragma unroll
    for (int i = 0; i < 4; ++i) Ar[i] = rowAs[ty * 4 + i];

    float minv[4];
    int   mini[4];
    #pragma unroll
    for (int i = 0; i < 4; ++i) { minv[i] = 3.4e38f; mini[i] = 0; }

    for (int kt = 0; kt < KR; kt += 64) {
        float acc[4][4] = {};
        for (int cc = 0; cc < EDIM; cc += 16) {
            {
                int n = tid >> 2, cp = (tid & 3) * 4;
                float4 v = *(const float4*)(ze + (size_t)(n0 + n) * EDIM + cc + cp);
                xs[cp + 0][n] = v.x; xs[cp + 1][n] = v.y;
                xs[cp + 2][n] = v.z; xs[cp + 3][n] = v.w;
            }
            {
                int k = tid >> 2, cp = (tid & 3) * 4;
                float4 v = *(const float4*)(embed + (size_t)(kbase + kt + k) * EDIM + cc + cp);
                es[cp + 0][k] = v.x; es[cp + 1][k] = v.y;
                es[cp + 2][k] = v.z; es[cp + 3][k] = v.w;
            }
            __syncthreads();
            #pragma unroll
            for (int c = 0; c < 16; ++c) {
                float xf[4], ef[4];
                #pragma unroll
                for (int i2 = 0; i2 < 4; ++i2) xf[i2] = xs[c][ty * 4 + i2];
                #pragma unroll
                for (int j2 = 0; j2 < 4; ++j2) ef[j2] = es[c][tx * 4 + j2];
                #pragma unroll
                for (int i2 = 0; i2 < 4; ++i2)
                    #pragma unroll
                    for (int j2 = 0; j2 < 4; ++j2)
                        acc[i2][j2] += xf[i2] * ef[j2];
            }
            __syncthreads();
        }
        #pragma unroll
        for (int j = 0; j < 4; ++j) {
            int k = kbase + kt + tx * 4 + j;
            #pragma unroll
            for (int i = 0; i < 4; ++i) {
                float d = Ar[i] - 2.0f * acc[i][j];
                if (d < minv[i]) { minv[i] = d; mini[i] = k; }
            }
        }
    }
    #pragma unroll
    for (int i = 0; i < 4; ++i) {
        float v = minv[i]; int ix = mini[i];
        #pragma unroll
        for (int m = 8; m >= 1; m >>= 1) {
            float ov = __shfl_xor(v, m);
            int   oi = __shfl_xor(ix, m);
            if (ov < v || (ov == v && oi < ix)) { v = ov; ix = oi; }
        }
        if (tx == 0) {
            int n = n0 + ty * 4 + i;
            pval[(size_t)blockIdx.y * NPOS + n] = v;
            pidx[(size_t)blockIdx.y * NPOS + n] = ix;
        }
    }
}

__global__ __launch_bounds__(256) void vq_reduce_argmin_kernel(
    const float* __restrict__ pval, const int* __restrict__ pidx,
    int S, int* __restrict__ fidx, float* __restrict__ out_ind)
{
    int n = blockIdx.x * 256 + threadIdx.x;
    float v = pval[n]; int ix = pidx[n];
    for (int ks = 1; ks < S; ++ks) {
        float ov = pval[(size_t)ks * NPOS + n];
        int   oi = pidx[(size_t)ks * NPOS + n];
        if (ov < v || (ov == v && oi < ix)) { v = ov; ix = oi; }
    }
    fidx[n] = ix;
    out_ind[n] = (float)ix;
}

__global__ __launch_bounds__(256) void vq_gather_diff_kernel(
    const float* __restrict__ embed, const int* __restrict__ fidx,
    float* __restrict__ zq, float* __restrict__ partials)
{
    int tid = threadIdx.x;
    int n0 = blockIdx.x * 32;
    float s = 0.f;
    for (int r = 0; r < 32; ++r) {
        int n = n0 + r;
        int idx = fidx[n];
        float e = embed[(size_t)idx * EDIM + tid];
        float v = zq[(size_t)n * EDIM + tid];
        float d = e - v;
        s += d * d;
        zq[(size_t)n * EDIM + tid] = e;
    }
    __shared__ float red[4];
    #pragma unroll
    for (int off = 32; off >= 1; off >>= 1) s += __shfl_down(s, off);
    if ((tid & 63) == 0) red[tid >> 6] = s;
    __syncthreads();
    if (tid == 0) partials[blockIdx.x] = red[0] + red[1] + red[2] + red[3];
}

__global__ __launch_bounds__(256) void vq_finalize_kernel(
    const float* __restrict__ partials, float* __restrict__ out_diff)
{
    int tid = threadIdx.x;
    float s = partials[tid];
    __shared__ float red[4];
    #pragma unroll
    for (int off = 32; off >= 1; off >>= 1) s += __shfl_down(s, off);
    if ((tid & 63) == 0) red[tid >> 6] = s;
    __syncthreads();
    if (tid == 0)
        out_diff[0] = (red[0] + red[1] + red[2] + red[3]) / (float)(NPOS * EDIM);
}

// ---------------------------------------------------------------------------
extern "C" void kernel_launch(void* const* d_in, const int* in_sizes, int n_in,
                              void* d_out, int out_size, void* d_ws, size_t ws_size,
                              hipStream_t stream)
{
    const float* z     = (const float*)d_in[0];
    const float* w     = (const float*)d_in[1];
    const float* bias  = (const float*)d_in[2];
    const float* embed = (const float*)d_in[3];

    float* out      = (float*)d_out;
    float* zq       = out;                       // [8192][256]; z_e then z_q
    float* out_diff = out + (size_t)NPOS * EDIM;
    float* out_ind  = out_diff + 1;              // [8192] indices as float

    char* wsb = (char*)d_ws;
    const size_t SZ_ZP   = (size_t)NPOS * CIN * 2;   // 8 MB (zph / zpl each)
    const size_t SZ_WP   = (size_t)EDIM * CIN * 2;   // 256 KB (wph / wpl each)
    const size_t SZ_GEH  = (size_t)KCB * EDIM * 2;   // 4 MB
    const size_t SZ_GXH  = (size_t)NPOS * EDIM * 2;  // 4 MB
    // layout: [phase A: zph zpl wph wpl | geh | gxh (persistent)]; phase B
    // (pv1 pi1 pv2 pi2 fidx partials ~2.1 MB) aliases the zph/zpl region.
    // gxh is written by proj_mfma (while zph/zpl still live) so it gets its
    // own region after geh: NEED = 16.5 + 4 + 4 = 24.5 MB <= 25.3 MB (r4).
    const size_t OFF_GEH = 2 * SZ_ZP + 2 * SZ_WP;    // 16.5 MB
    const size_t OFF_GXH = OFF_GEH + SZ_GEH;         // 20.5 MB
    const size_t NEED = OFF_GXH + SZ_GXH;            // 24.5 MB

    if (ws_size >= NEED) {
        // ---- MFMA path ----
        _Float16* zph = (_Float16*)wsb;
        _Float16* zpl = zph + SZ_ZP / 2;
        _Float16* wph = zpl + SZ_ZP / 2;
        _Float16* wpl = wph + SZ_WP / 2;
        _Float16* geh = (_Float16*)(wsb + OFF_GEH);
        _Float16* gxh = (_Float16*)(wsb + OFF_GXH);
        // phase B (aliases zph/zpl region; starts after proj completes)
        float*    pv1  = (float*)wsb;
        int*      pi1  = (int*)(pv1 + (size_t)NSPLIT * NPOS);
        float*    pv2  = (float*)(pi1 + (size_t)NSPLIT * NPOS);
        int*      pi2  = (int*)(pv2 + (size_t)NSPLIT * NPOS);
        int*      fidx = (int*)(pi2 + (size_t)NSPLIT * NPOS);
        float*    partials = (float*)(fidx + NPOS);   // 512 floats

        vq_proj_split_kernel<<<dim3(3136), dim3(256), 0, stream>>>(
            z, w, embed, zph, zpl, wph, wpl, geh);
        vq_proj_mfma_kernel<<<dim3(128, 4), dim3(256), 0, stream>>>(
            zph, zpl, wph, wpl, bias, zq, gxh);
        vq_argmin_mfma7_kernel<<<dim3(64, NSPLIT), dim3(512), 0, stream>>>(
            gxh, geh, pv1, pi1, pv2, pi2);
        vq_rrg_kernel<<<dim3(512), dim3(256), 0, stream>>>(
            pv1, pi1, pv2, pi2, embed, zq, fidx, out_ind, partials);
        vq_finalize512_kernel<<<dim3(1), dim3(256), 0, stream>>>(partials, out_diff);
    } else {
        // ---- fallback: round-3 validated fp32 path ----
        int S = 8;
        while (S > 1 && ws_size < (size_t)(2 * KCB + 256 + 2 * (size_t)S * NPOS) * 4) S >>= 1;
        float* W        = (float*)d_ws;
        float* rowA     = W;
        float* pval     = rowA + KCB;
        int*   pidx     = (int*)(pval + (size_t)S * NPOS);
        int*   fidx     = (int*)(pval + 2 * (size_t)S * NPOS);
        float* partials = (float*)(fidx + NPOS);

        vq_proj_kernel<<<dim3(128, 4), dim3(256), 0, stream>>>(z, w, bias, zq);
        vq_rownorm_kernel<<<dim3(2048), dim3(256), 0, stream>>>(zq, rowA);
        vq_argmin_kernel<<<dim3(128, S), dim3(256), 0, stream>>>(zq, embed, rowA, pval, pidx);
        vq_reduce_argmin_kernel<<<dim3(32), dim3(256), 0, stream>>>(pval, pidx, S, fidx, out_ind);
        vq_gather_diff_kernel<<<dim3(256), dim3(256), 0, stream>>>(embed, fidx, zq, partials);
        vq_finalize_kernel<<<dim3(1), dim3(256), 0, stream>>>(partials, out_diff);
    }
}